// Round 14
// baseline (271.802 us; speedup 1.0000x reference)
//
#include <hip/hip_runtime.h>
#include <math.h>

#define NN   4096
#define MM   1024
#define NNZC 65536
#define DD   512
#define HH   8
#define DHH  64
#define DFFC 2048
#define NSPLIT 8

typedef short bf16x8 __attribute__((ext_vector_type(8)));
typedef float f32x4  __attribute__((ext_vector_type(4)));

static __device__ inline unsigned short f2bf(float f) {
  union { float f; unsigned int u; } v; v.f = f;
  unsigned int r = v.u + 0x7fff + ((v.u >> 16) & 1);   // RNE
  return (unsigned short)(r >> 16);
}
static __device__ inline float bf2f(unsigned short u) {
  return __uint_as_float((unsigned int)u << 16);
}

__device__ inline void gload16(const void* g, void* l) {
  __builtin_amdgcn_global_load_lds(
      (const __attribute__((address_space(1))) void*)g,
      (__attribute__((address_space(3))) void*)l, 16, 0, 0);
}

// ---------------- utility ----------------
__device__ inline void atomicMaxF(float* addr, float val) {
  if (val >= 0.f) atomicMax((int*)addr, __float_as_int(val));
  else            atomicMin((unsigned int*)addr, __float_as_uint(val));
}

// ---------------- init ----------------
__global__ void init_kernel(float* amax, float* den, int* DnCnt, int* BnCnt,
                            int* node_cur, int* edge_cur) {
  int i = blockIdx.x * 256 + threadIdx.x;
  if (i < NN) { amax[i] = -INFINITY; den[i] = 0.f; DnCnt[i] = 0; node_cur[i] = 0; }
  if (i < MM) { BnCnt[i] = 0; edge_cur[i] = 0; }
}

// ---------------- batched fp32 -> bf16 convert (7 segments, 1 launch) ----------------
__global__ __launch_bounds__(256) void f2b_multi(
    const float* s0, unsigned short* d0, int n0,
    const float* s1, unsigned short* d1, int n1,
    const float* s2, unsigned short* d2, int n2,
    const float* s3, unsigned short* d3, int n3,
    const float* s4, unsigned short* d4, int n4,
    const float* s5, unsigned short* d5, int n5,
    const float* s6, unsigned short* d6, int n6) {
  const float* in; unsigned short* out; int n8;
  switch (blockIdx.y) {
    case 0: in=s0; out=d0; n8=n0; break;
    case 1: in=s1; out=d1; n8=n1; break;
    case 2: in=s2; out=d2; n8=n2; break;
    case 3: in=s3; out=d3; n8=n3; break;
    case 4: in=s4; out=d4; n8=n4; break;
    case 5: in=s5; out=d5; n8=n5; break;
    default: in=s6; out=d6; n8=n6; break;
  }
  for (int i = blockIdx.x*256 + threadIdx.x; i < n8; i += gridDim.x*256) {
    float4 v0 = *(const float4*)&in[(size_t)i*8];
    float4 v1 = *(const float4*)&in[(size_t)i*8 + 4];
    unsigned short w[8];
    w[0]=f2bf(v0.x); w[1]=f2bf(v0.y); w[2]=f2bf(v0.z); w[3]=f2bf(v0.w);
    w[4]=f2bf(v1.x); w[5]=f2bf(v1.y); w[6]=f2bf(v1.z); w[7]=f2bf(v1.w);
    *(ulonglong2*)&out[(size_t)i*8] = *(ulonglong2*)w;
  }
}

// ---------------- bf16 MFMA NT GEMM, 128x128 tile (ff1) ----------------
__global__ __launch_bounds__(256) void gemm_bt_bf16(
    const unsigned short* __restrict__ A, const unsigned short* __restrict__ B,
    const float* __restrict__ bias, float* __restrict__ Cf,
    unsigned short* __restrict__ Cb, int N, int K, int relu) {
  __shared__ __align__(16) unsigned short Al[128*64];
  __shared__ __align__(16) unsigned short Bl[128*64];
  const int t = threadIdx.x;
  const int w = t >> 6, l = t & 63;
  const int lg = l >> 4, lid = l & 15;
  const int wr = w >> 1, wc = w & 1;
  const int bm = blockIdx.x * 128, bn = blockIdx.y * 128;

  f32x4 acc[4][4];
  #pragma unroll
  for (int mi = 0; mi < 4; ++mi)
    #pragma unroll
    for (int ni = 0; ni < 4; ++ni) acc[mi][ni] = (f32x4)0.f;

  for (int k0 = 0; k0 < K; k0 += 64) {
    #pragma unroll
    for (int i = 0; i < 4; ++i) {
      int cid = i*256 + t;
      int row = cid >> 3, cp = cid & 7;
      int gc = cp ^ (row & 7);
      gload16(&A[(size_t)(bm + row)*K + k0 + gc*8], &Al[cid*8]);
      gload16(&B[(size_t)(bn + row)*K + k0 + gc*8], &Bl[cid*8]);
    }
    asm volatile("s_waitcnt vmcnt(0)" ::: "memory");
    __syncthreads();
    #pragma unroll
    for (int ks = 0; ks < 2; ++ks) {
      bf16x8 af[4], bfr[4];
      #pragma unroll
      for (int mi = 0; mi < 4; ++mi) {
        int r = wr*64 + mi*16 + lid;
        af[mi] = *(const bf16x8*)&Al[r*64 + ((ks*4 + lg) ^ (r & 7))*8];
      }
      #pragma unroll
      for (int ni = 0; ni < 4; ++ni) {
        int r = wc*64 + ni*16 + lid;
        bfr[ni] = *(const bf16x8*)&Bl[r*64 + ((ks*4 + lg) ^ (r & 7))*8];
      }
      __builtin_amdgcn_s_setprio(1);
      #pragma unroll
      for (int mi = 0; mi < 4; ++mi)
        #pragma unroll
        for (int ni = 0; ni < 4; ++ni)
          acc[mi][ni] = __builtin_amdgcn_mfma_f32_16x16x32_bf16(af[mi], bfr[ni], acc[mi][ni], 0, 0, 0);
      __builtin_amdgcn_s_setprio(0);
    }
    __syncthreads();
  }

  #pragma unroll
  for (int ni = 0; ni < 4; ++ni) {
    int col = bn + wc*64 + ni*16 + lid;
    float bv = bias ? bias[col] : 0.f;
    #pragma unroll
    for (int mi = 0; mi < 4; ++mi) {
      #pragma unroll
      for (int rg = 0; rg < 4; ++rg) {
        int row = bm + wr*64 + mi*16 + lg*4 + rg;
        float v = acc[mi][ni][rg] + bv;
        if (relu) v = fmaxf(v, 0.f);
        if (Cf) Cf[(size_t)row*N + col] = v;
        if (Cb) Cb[(size_t)row*N + col] = f2bf(v);
      }
    }
  }
}

// ---------------- bf16 MFMA NT GEMM, 128x64 tile (small-N GEMMs) ----------------
// VtbOpt: if non-null and bn >= 1024 (V-plane of qkv), write the tile TRANSPOSED
// into Vtb[h][d][tok] instead of Cb (fuses conv_vt; identical rounding).
__global__ __launch_bounds__(256) void gemm_bt_bf16_n64(
    const unsigned short* __restrict__ A, const unsigned short* __restrict__ B,
    const float* __restrict__ bias, unsigned short* __restrict__ Cb, int N, int K,
    unsigned short* __restrict__ VtbOpt) {
  __shared__ __align__(16) unsigned short Al[128*64];
  __shared__ __align__(16) unsigned short Bl[64*64];
  const int t = threadIdx.x;
  const int w = t >> 6, l = t & 63;
  const int lg = l >> 4, lid = l & 15;
  const int wr = w >> 1, wc = w & 1;
  const int bm = blockIdx.x * 128, bn = blockIdx.y * 64;

  f32x4 acc[4][2];
  #pragma unroll
  for (int mi = 0; mi < 4; ++mi)
    #pragma unroll
    for (int ni = 0; ni < 2; ++ni) acc[mi][ni] = (f32x4)0.f;

  for (int k0 = 0; k0 < K; k0 += 64) {
    #pragma unroll
    for (int i = 0; i < 4; ++i) {
      int cid = i*256 + t;
      int row = cid >> 3, cp = cid & 7;
      int gc = cp ^ (row & 7);
      gload16(&A[(size_t)(bm + row)*K + k0 + gc*8], &Al[cid*8]);
    }
    #pragma unroll
    for (int i = 0; i < 2; ++i) {
      int cid = i*256 + t;
      int row = cid >> 3, cp = cid & 7;
      int gc = cp ^ (row & 7);
      gload16(&B[(size_t)(bn + row)*K + k0 + gc*8], &Bl[cid*8]);
    }
    asm volatile("s_waitcnt vmcnt(0)" ::: "memory");
    __syncthreads();
    #pragma unroll
    for (int ks = 0; ks < 2; ++ks) {
      bf16x8 af[4], bfr[2];
      #pragma unroll
      for (int mi = 0; mi < 4; ++mi) {
        int r = wr*64 + mi*16 + lid;
        af[mi] = *(const bf16x8*)&Al[r*64 + ((ks*4 + lg) ^ (r & 7))*8];
      }
      #pragma unroll
      for (int ni = 0; ni < 2; ++ni) {
        int r = wc*32 + ni*16 + lid;
        bfr[ni] = *(const bf16x8*)&Bl[r*64 + ((ks*4 + lg) ^ (r & 7))*8];
      }
      __builtin_amdgcn_s_setprio(1);
      #pragma unroll
      for (int mi = 0; mi < 4; ++mi)
        #pragma unroll
        for (int ni = 0; ni < 2; ++ni)
          acc[mi][ni] = __builtin_amdgcn_mfma_f32_16x16x32_bf16(af[mi], bfr[ni], acc[mi][ni], 0, 0, 0);
      __builtin_amdgcn_s_setprio(0);
    }
    __syncthreads();
  }

  if (VtbOpt && bn >= 1024) {
    // transposed write: Vtb[h][d][tok], 4 consecutive tokens per ushort4
    #pragma unroll
    for (int ni = 0; ni < 2; ++ni) {
      int col = bn + wc*32 + ni*16 + lid;
      float bv = bias ? bias[col] : 0.f;
      int d = col - 1024;
      int h = d >> 6, dd = d & 63;
      #pragma unroll
      for (int mi = 0; mi < 4; ++mi) {
        int tok0 = bm + wr*64 + mi*16 + lg*4;
        ushort4 w4;
        w4.x = f2bf(acc[mi][ni][0] + bv);
        w4.y = f2bf(acc[mi][ni][1] + bv);
        w4.z = f2bf(acc[mi][ni][2] + bv);
        w4.w = f2bf(acc[mi][ni][3] + bv);
        *(ushort4*)&VtbOpt[(size_t)h*64*NN + (size_t)dd*NN + tok0] = w4;
      }
    }
  } else {
    #pragma unroll
    for (int ni = 0; ni < 2; ++ni) {
      int col = bn + wc*32 + ni*16 + lid;
      float bv = bias ? bias[col] : 0.f;
      #pragma unroll
      for (int mi = 0; mi < 4; ++mi) {
        #pragma unroll
        for (int rg = 0; rg < 4; ++rg) {
          int row = bm + wr*64 + mi*16 + lg*4 + rg;
          Cb[(size_t)row*N + col] = f2bf(acc[mi][ni][rg] + bv);
        }
      }
    }
  }
}

// ---------------- merged row dots: s_node (xl rows) and s_edge (el rows), 1 launch --------
__global__ __launch_bounds__(256) void rowdot_both(const unsigned short* __restrict__ xlb,
    const unsigned short* __restrict__ elb, const float* __restrict__ att,
    float* __restrict__ s_node, float* __restrict__ s_edge) {
  int w = (blockIdx.x * 256 + threadIdx.x) >> 6;
  int lane = threadIdx.x & 63;
  const unsigned short* xr;
  const float* vec;
  if (w < NN) { xr = &xlb[(size_t)w * DD]; vec = att; }
  else        { xr = &elb[(size_t)(w - NN) * DD]; vec = att + DD; }
  float s = 0.f;
  #pragma unroll
  for (int j = 0; j < 8; ++j) s += bf2f(xr[lane + 64*j]) * vec[lane + 64*j];
  #pragma unroll
  for (int off = 1; off < 64; off <<= 1) s += __shfl_xor(s, off, 64);
  if (lane == 0) {
    if (w < NN) s_node[w] = s;
    else        s_edge[w - NN] = s;
  }
}

// ---------------- incidence pass 1 ----------------
__global__ void incidence_pass1(const int* __restrict__ node_idx, const int* __restrict__ edge_idx,
    const float* __restrict__ s_node, const float* __restrict__ s_edge,
    float* __restrict__ a_buf, float* amax, int* DnCnt, int* BnCnt) {
  int i = blockIdx.x * 256 + threadIdx.x;
  if (i >= NNZC) return;
  int n = node_idx[i], m = edge_idx[i];
  float a = s_node[n] + s_edge[m];
  a = (a >= 0.f) ? a : 0.2f * a;
  a_buf[i] = a;
  atomicMaxF(&amax[n], a);
  atomicAdd(&DnCnt[n], 1);
  atomicAdd(&BnCnt[m], 1);
}

// ---------------- dual exclusive scan: block 0 scans DnCnt[NN], block 1 BnCnt[MM] ----------
__global__ __launch_bounds__(1024) void exscan2_kernel(const int* __restrict__ inA,
    int* __restrict__ outA, int nA, const int* __restrict__ inB, int* __restrict__ outB, int nB) {
  const int* in; int* out; int n;
  if (blockIdx.x == 0) { in = inA; out = outA; n = nA; }
  else                 { in = inB; out = outB; n = nB; }
  __shared__ int sums[1024];
  const int t = threadIdx.x;
  const int chunk = (n + 1023) >> 10;
  const int start = t * chunk;
  const int stop  = min(start + chunk, n);
  int local = 0;
  for (int i = start; i < stop; ++i) local += in[i];
  sums[t] = local;
  __syncthreads();
  for (int o = 1; o < 1024; o <<= 1) {
    int v = (t >= o) ? sums[t - o] : 0;
    __syncthreads();
    sums[t] += v;
    __syncthreads();
  }
  int run = (t == 0) ? 0 : sums[t - 1];
  for (int i = start; i < stop; ++i) { out[i] = run; run += in[i]; }
  if (t == 1023) out[n] = sums[1023];
}

// ---------------- incidence pass 2 ----------------
__global__ void incidence_pass2(const int* __restrict__ node_idx, const int* __restrict__ edge_idx,
    float* __restrict__ a_buf, const float* __restrict__ amax, float* den,
    const int* __restrict__ node_off, const int* __restrict__ edge_off,
    int* node_cur, int* edge_cur, int* node_list, int* edge_list) {
  int i = blockIdx.x * 256 + threadIdx.x;
  if (i >= NNZC) return;
  int n = node_idx[i], m = edge_idx[i];
  float e = __expf(a_buf[i] - amax[n]);
  a_buf[i] = e;
  atomicAdd(&den[n], e);
  int pn = atomicAdd(&node_cur[n], 1);
  node_list[node_off[n] + pn] = i;
  int pm = atomicAdd(&edge_cur[m], 1);
  edge_list[edge_off[m] + pm] = i;
}

// ---------------- edge gather (bf16 xl in, bf16 ef out) ----------------
__global__ __launch_bounds__(256) void gather_edge(const int* __restrict__ edge_off,
    const int* __restrict__ edge_list, const int* __restrict__ node_idx,
    const float* __restrict__ a_buf, const float* __restrict__ den,
    const unsigned short* __restrict__ xlb, unsigned short* __restrict__ efb) {
  int m = blockIdx.x;
  int t = threadIdx.x;
  int beg = edge_off[m], end = edge_off[m+1];
  int cnt = end - beg;
  float Binv = (cnt > 0) ? (1.0f / (float)cnt) : 0.f;
  __shared__ int   ln_[128];
  __shared__ float lw_[128];
  float acc0 = 0.f, acc1 = 0.f;
  for (int c = beg; c < end; c += 128) {
    int nchunk = min(128, end - c);
    if (t < nchunk) {
      int i = edge_list[c + t];
      int n = node_idx[i];
      ln_[t] = n;
      lw_[t] = a_buf[i] / (den[n] + 1e-16f) * Binv;
    }
    __syncthreads();
    float a0 = 0.f, a1 = 0.f, b0 = 0.f, b1 = 0.f;
    int j = 0;
    for (; j + 1 < nchunk; j += 2) {
      float w0 = lw_[j], w1 = lw_[j+1];
      const unsigned short* r0 = &xlb[(size_t)ln_[j]   * DD];
      const unsigned short* r1 = &xlb[(size_t)ln_[j+1] * DD];
      a0 += w0 * bf2f(r0[t]);       b0 += w0 * bf2f(r0[t + 256]);
      a1 += w1 * bf2f(r1[t]);       b1 += w1 * bf2f(r1[t + 256]);
    }
    if (j < nchunk) {
      float w0 = lw_[j];
      const unsigned short* r0 = &xlb[(size_t)ln_[j] * DD];
      a0 += w0 * bf2f(r0[t]);       b0 += w0 * bf2f(r0[t + 256]);
    }
    acc0 += a0 + a1;
    acc1 += b0 + b1;
    __syncthreads();
  }
  efb[(size_t)m * DD + t]       = f2bf(acc0);
  efb[(size_t)m * DD + t + 256] = f2bf(acc1);
}

// ---------------- node gather + fused LN1: x1 = LN(x + conv), bf16 copy ----------------
__global__ __launch_bounds__(256) void gather_node_ln(const int* __restrict__ node_off,
    const int* __restrict__ node_list, const int* __restrict__ edge_idx,
    const float* __restrict__ a_buf, const float* __restrict__ den,
    const unsigned short* __restrict__ efb, const float* __restrict__ bias_h,
    const float* __restrict__ x, const float* __restrict__ g, const float* __restrict__ be,
    float* __restrict__ x1, unsigned short* __restrict__ x1b) {
  int n = blockIdx.x;
  int t = threadIdx.x;
  int beg = node_off[n], end = node_off[n+1];
  int cnt = end - beg;
  float Dinv = (cnt > 0) ? (1.0f / (float)cnt) : 0.f;
  float wscale = Dinv / (den[n] + 1e-16f);
  __shared__ int   le_[128];
  __shared__ float lw_[128];
  float acc0 = 0.f, acc1 = 0.f;
  for (int c = beg; c < end; c += 128) {
    int nchunk = min(128, end - c);
    if (t < nchunk) {
      int i = node_list[c + t];
      le_[t] = edge_idx[i];
      lw_[t] = a_buf[i] * wscale;
    }
    __syncthreads();
    float a0 = 0.f, a1 = 0.f, b0 = 0.f, b1 = 0.f;
    int j = 0;
    for (; j + 1 < nchunk; j += 2) {
      float w0 = lw_[j], w1 = lw_[j+1];
      const unsigned short* r0 = &efb[(size_t)le_[j]   * DD];
      const unsigned short* r1 = &efb[(size_t)le_[j+1] * DD];
      a0 += w0 * bf2f(r0[t]);       b0 += w0 * bf2f(r0[t + 256]);
      a1 += w1 * bf2f(r1[t]);       b1 += w1 * bf2f(r1[t + 256]);
    }
    if (j < nchunk) {
      float w0 = lw_[j];
      const unsigned short* r0 = &efb[(size_t)le_[j] * DD];
      a0 += w0 * bf2f(r0[t]);       b0 += w0 * bf2f(r0[t + 256]);
    }
    acc0 += a0 + a1;
    acc1 += b0 + b1;
    __syncthreads();
  }
  // fused LN: v = x + (conv + bias_h)
  float v0 = x[(size_t)n*DD + t]       + acc0 + bias_h[t];
  float v1 = x[(size_t)n*DD + t + 256] + acc1 + bias_h[t + 256];
  __shared__ float red[4];
  __shared__ float mu_s, rstd_s;
  float s = v0 + v1;
  #pragma unroll
  for (int off = 1; off < 64; off <<= 1) s += __shfl_xor(s, off, 64);
  int wid = t >> 6;
  if ((t & 63) == 0) red[wid] = s;
  __syncthreads();
  if (t == 0) mu_s = (red[0] + red[1] + red[2] + red[3]) / 512.f;
  __syncthreads();
  float mu = mu_s;
  float d0 = v0 - mu, d1 = v1 - mu;
  float vs = d0*d0 + d1*d1;
  #pragma unroll
  for (int off = 1; off < 64; off <<= 1) vs += __shfl_xor(vs, off, 64);
  if ((t & 63) == 0) red[wid] = vs;
  __syncthreads();
  if (t == 0) rstd_s = rsqrtf((red[0] + red[1] + red[2] + red[3]) / 512.f + 1e-5f);
  __syncthreads();
  float rs = rstd_s;
  float o0 = d0 * rs * g[t]       + be[t];
  float o1 = d1 * rs * g[t + 256] + be[t + 256];
  x1[(size_t)n*DD + t]        = o0;
  x1[(size_t)n*DD + t + 256]  = o1;
  x1b[(size_t)n*DD + t]       = f2bf(o0);
  x1b[(size_t)n*DD + t + 256] = f2bf(o1);
}

// ---------------- LayerNorm(a + b), b fp32 or bf16; optional bf16 copy ----------------
__global__ __launch_bounds__(256) void ln_residual(const float* __restrict__ a,
    const float* __restrict__ b, const unsigned short* __restrict__ bB,
    const float* __restrict__ g, const float* __restrict__ be,
    float* __restrict__ out, unsigned short* __restrict__ outb) {
  int r = blockIdx.x;
  int t = threadIdx.x;
  float b0 = b ? b[(size_t)r*DD + t]       : bf2f(bB[(size_t)r*DD + t]);
  float b1 = b ? b[(size_t)r*DD + t + 256] : bf2f(bB[(size_t)r*DD + t + 256]);
  float v0 = a[(size_t)r*DD + t]       + b0;
  float v1 = a[(size_t)r*DD + t + 256] + b1;
  __shared__ float red[4];
  __shared__ float mu_s, rstd_s;
  float s = v0 + v1;
  #pragma unroll
  for (int off = 1; off < 64; off <<= 1) s += __shfl_xor(s, off, 64);
  int wid = t >> 6;
  if ((t & 63) == 0) red[wid] = s;
  __syncthreads();
  if (t == 0) mu_s = (red[0] + red[1] + red[2] + red[3]) / 512.f;
  __syncthreads();
  float mu = mu_s;
  float d0 = v0 - mu, d1 = v1 - mu;
  float vs = d0*d0 + d1*d1;
  #pragma unroll
  for (int off = 1; off < 64; off <<= 1) vs += __shfl_xor(vs, off, 64);
  if ((t & 63) == 0) red[wid] = vs;
  __syncthreads();
  if (t == 0) rstd_s = rsqrtf((red[0] + red[1] + red[2] + red[3]) / 512.f + 1e-5f);
  __syncthreads();
  float rs = rstd_s;
  float o0 = d0 * rs * g[t]       + be[t];
  float o1 = d1 * rs * g[t + 256] + be[t + 256];
  out[(size_t)r*DD + t]       = o0;
  out[(size_t)r*DD + t + 256] = o1;
  if (outb) {
    outb[(size_t)r*DD + t]       = f2bf(o0);
    outb[(size_t)r*DD + t + 256] = f2bf(o1);
  }
}

// ---------------- fused final 2 LayerNorms: x3=LN(x2+ffo); out=LN(x1+x3) ----------------
__global__ __launch_bounds__(256) void ln_final2(const float* __restrict__ x2,
    const unsigned short* __restrict__ ffob, const float* __restrict__ x1,
    const float* __restrict__ g1, const float* __restrict__ b1,
    const float* __restrict__ g2, const float* __restrict__ b2,
    float* __restrict__ out) {
  int r = blockIdx.x;
  int t = threadIdx.x;
  __shared__ float red[4];
  __shared__ float sh0, sh1;
  int wid = t >> 6;
  float v0 = x2[(size_t)r*DD + t]       + bf2f(ffob[(size_t)r*DD + t]);
  float v1 = x2[(size_t)r*DD + t + 256] + bf2f(ffob[(size_t)r*DD + t + 256]);
  float s = v0 + v1;
  #pragma unroll
  for (int off = 1; off < 64; off <<= 1) s += __shfl_xor(s, off, 64);
  if ((t & 63) == 0) red[wid] = s;
  __syncthreads();
  if (t == 0) sh0 = (red[0] + red[1] + red[2] + red[3]) / 512.f;
  __syncthreads();
  float mu = sh0;
  float d0 = v0 - mu, d1 = v1 - mu;
  float vs = d0*d0 + d1*d1;
  #pragma unroll
  for (int off = 1; off < 64; off <<= 1) vs += __shfl_xor(vs, off, 64);
  if ((t & 63) == 0) red[wid] = vs;
  __syncthreads();
  if (t == 0) sh1 = rsqrtf((red[0] + red[1] + red[2] + red[3]) / 512.f + 1e-5f);
  __syncthreads();
  float rs = sh1;
  float x30 = d0 * rs * g1[t]       + b1[t];
  float x31 = d1 * rs * g1[t + 256] + b1[t + 256];
  __syncthreads();
  float u0 = x1[(size_t)r*DD + t]       + x30;
  float u1 = x1[(size_t)r*DD + t + 256] + x31;
  s = u0 + u1;
  #pragma unroll
  for (int off = 1; off < 64; off <<= 1) s += __shfl_xor(s, off, 64);
  if ((t & 63) == 0) red[wid] = s;
  __syncthreads();
  if (t == 0) sh0 = (red[0] + red[1] + red[2] + red[3]) / 512.f;
  __syncthreads();
  mu = sh0;
  d0 = u0 - mu; d1 = u1 - mu;
  vs = d0*d0 + d1*d1;
  #pragma unroll
  for (int off = 1; off < 64; off <<= 1) vs += __shfl_xor(vs, off, 64);
  if ((t & 63) == 0) red[wid] = vs;
  __syncthreads();
  if (t == 0) sh1 = rsqrtf((red[0] + red[1] + red[2] + red[3]) / 512.f + 1e-5f);
  __syncthreads();
  rs = sh1;
  out[(size_t)r*DD + t]       = d0 * rs * g2[t]       + b2[t];
  out[(size_t)r*DD + t + 256] = d1 * rs * g2[t + 256] + b2[t + 256];
}

// ---------------- MFMA flash attention partial (split-K), KVBLK=64, swapped-QK^T ----
// Round-11 structure (best measured); NSPLIT=8 for occupancy.
__global__ __launch_bounds__(256) void attn_mfma_part(const unsigned short* __restrict__ qkvbb,
                                                      const unsigned short* __restrict__ Vtb,
                                                      unsigned short* __restrict__ Opartb,
                                                      float* __restrict__ ml) {
  const int head = blockIdx.y;
  const int z = blockIdx.z;
  const int q0 = blockIdx.x * 64;
  const int t = threadIdx.x;
  const int w = t >> 6;
  const int l = t & 63;
  const int lg = l >> 4;
  const int lid = l & 15;
  const float sc = 0.125f * 1.44269504f;    // 1/sqrt(64) * log2(e)
  const float THRraw = 44.36f;              // 8 / sc

  __shared__ __align__(16) unsigned short Kl[64*64];
  __shared__ __align__(16) unsigned short Vl[64*64];

  bf16x8 qa[2];
  {
    const int qrow = q0 + w*16 + lid;
    const unsigned short* qp = &qkvbb[(size_t)qrow*1536 + head*64];
    qa[0] = *(const bf16x8*)&qp[lg*8];
    qa[1] = *(const bf16x8*)&qp[32 + lg*8];
  }

  float m = -1e30f, msc = -1e30f, lsum = 0.f;
  f32x4 o[4];
  #pragma unroll
  for (int dt = 0; dt < 4; ++dt) o[dt] = (f32x4)0.f;

  const unsigned short* Kh = qkvbb + 512 + head*64;          // row stride 1536
  const unsigned short* Vh = Vtb + (size_t)head*64*NN;
  const int kt0 = z * (NN / NSPLIT);
  const int kt1 = kt0 + (NN / NSPLIT);

  const int srow0 = t >> 3,        scc = (t & 7) * 8;
  const int srow1 = 32 + (t >> 3);
  const int sdst0 = (srow0*64 + scc) ^ ((srow0 & 7) << 3);
  const int sdst1 = (srow1*64 + scc) ^ ((srow1 & 7) << 3);
  const int kperm0 = 8*((srow0>>2)&3) + 4*((srow0>>4)&1) + (srow0&3) + 32*(srow0>>5);
  const int kperm1 = 8*((srow1>>2)&3) + 4*((srow1>>4)&1) + (srow1&3) + 32*(srow1>>5);
  ulonglong2 kreg0, kreg1, vreg0, vreg1;

#define LOADKV(ktv) do { \
    kreg0 = *(const ulonglong2*)&Kh[(size_t)((ktv) + kperm0)*1536 + scc]; \
    vreg0 = *(const ulonglong2*)&Vh[(size_t)srow0*NN + (ktv) + scc]; \
    kreg1 = *(const ulonglong2*)&Kh[(size_t)((ktv) + kperm1)*1536 + scc]; \
    vreg1 = *(const ulonglong2*)&Vh[(size_t)srow1*NN + (ktv) + scc]; \
  } while (0)
#define STORKV() do { \
    *(ulonglong2*)&Kl[sdst0] = kreg0; *(ulonglong2*)&Vl[sdst0] = vreg0; \
    *(ulonglong2*)&Kl[sdst1] = kreg1; *(ulonglong2*)&Vl[sdst1] = vreg1; \
  } while (0)

  LOADKV(kt0);
  STORKV();
  __syncthreads();

  for (int kt = kt0; kt < kt1; kt += 64) {
    const bool hn = (kt + 64) < kt1;
    if (hn) LOADKV(kt + 64);   // issue early; lands during compute (T14)

    // ---- S^T = K Q^T (swapped operands) ----
    f32x4 s[4];
    #pragma unroll
    for (int n = 0; n < 4; ++n) s[n] = (f32x4)0.f;
    __builtin_amdgcn_s_setprio(1);
    #pragma unroll
    for (int n = 0; n < 4; ++n) {
      int tok = n*16 + lid;
      #pragma unroll
      for (int hf = 0; hf < 2; ++hf) {
        int didx = (tok*64 + hf*32 + lg*8) ^ ((tok & 7) << 3);
        bf16x8 kb = *(const bf16x8*)&Kl[didx];
        s[n] = __builtin_amdgcn_mfma_f32_16x16x32_bf16(kb, qa[hf], s[n], 0, 0, 0);
      }
    }
    __builtin_amdgcn_s_setprio(0);

    // ---- in-register online softmax, raw units (q = lid per lane) ----
    float a0 = fmaxf(fmaxf(s[0][0], s[0][1]), s[0][2]);
    float a1 = fmaxf(fmaxf(s[0][3], s[1][0]), s[1][1]);
    float a2 = fmaxf(fmaxf(s[1][2], s[1][3]), s[2][0]);
    float a3 = fmaxf(fmaxf(s[2][1], s[2][2]), s[2][3]);
    float a4 = fmaxf(fmaxf(s[3][0], s[3][1]), s[3][2]);
    float mx = fmaxf(fmaxf(fmaxf(a0, a1), a2), fmaxf(fmaxf(a3, a4), s[3][3]));
    mx = fmaxf(mx, __shfl_xor(mx, 16, 64));
    mx = fmaxf(mx, __shfl_xor(mx, 32, 64));
    if (!__all(mx <= m + THRraw)) {
      float mn = fmaxf(m, mx);
      float c = exp2f((m - mn) * sc);
      m = mn;
      msc = m * sc;
      lsum *= c;
      #pragma unroll
      for (int r = 0; r < 4; ++r) {
        float cr = __shfl(c, lg*4 + r, 64);
        #pragma unroll
        for (int dt = 0; dt < 4; ++dt) o[dt][r] *= cr;
      }
    }
    float ps = 0.f;
    #pragma unroll
    for (int n = 0; n < 4; ++n)
      #pragma unroll
      for (int r = 0; r < 4; ++r) {
        float p = exp2f(fmaf(s[n][r], sc, -msc));
        s[n][r] = p;
        ps += p;
      }
    ps += __shfl_xor(ps, 16, 64);
    ps += __shfl_xor(ps, 32, 64);
    lsum += ps;

    // ---- P repack: fully in-lane (thanks to K row permutation) ----
    union { bf16x8 v; unsigned int u[4]; } pa[2];
    #pragma unroll
    for (int hf = 0; hf < 2; ++hf) {
      asm("v_cvt_pk_bf16_f32 %0, %1, %2" : "=v"(pa[hf].u[0]) : "v"(s[2*hf][0]),   "v"(s[2*hf][1]));
      asm("v_cvt_pk_bf16_f32 %0, %1, %2" : "=v"(pa[hf].u[1]) : "v"(s[2*hf][2]),   "v"(s[2*hf][3]));
      asm("v_cvt_pk_bf16_f32 %0, %1, %2" : "=v"(pa[hf].u[2]) : "v"(s[2*hf+1][0]), "v"(s[2*hf+1][1]));
      asm("v_cvt_pk_bf16_f32 %0, %1, %2" : "=v"(pa[hf].u[3]) : "v"(s[2*hf+1][2]), "v"(s[2*hf+1][3]));
    }

    // ---- O += P V ----
    __builtin_amdgcn_s_setprio(1);
    #pragma unroll
    for (int dt = 0; dt < 4; ++dt) {
      int drow = dt*16 + lid;
      #pragma unroll
      for (int hf = 0; hf < 2; ++hf) {
        int didx = (drow*64 + hf*32 + lg*8) ^ ((drow & 7) << 3);
        bf16x8 vb = *(const bf16x8*)&Vl[didx];
        o[dt] = __builtin_amdgcn_mfma_f32_16x16x32_bf16(pa[hf].v, vb, o[dt], 0, 0, 0);
      }
    }
    __builtin_amdgcn_s_setprio(0);

    __syncthreads();           // all waves done reading Kl/Vl
    if (hn) {
      STORKV();                // write prefetched tile
      __syncthreads();
    }
  }
#undef LOADKV
#undef STORKV

  // ---- epilogue: bf16 partial O (rows q=lg*4+r) + per-lane (msc, l) for q=lid ----
  #pragma unroll
  for (int r = 0; r < 4; ++r) {
    int q = q0 + w*16 + lg*4 + r;
    size_t base = ((size_t)(z*HH + head)*NN + q)*64;
    #pragma unroll
    for (int dt = 0; dt < 4; ++dt)
      Opartb[base + dt*16 + lid] = f2bf(o[dt][r]);
  }
  if (l < 16) {
    int q = q0 + w*16 + l;
    size_t mb = ((size_t)(z*HH + head)*NN + q)*2;
    ml[mb]     = msc;
    ml[mb + 1] = lsum;
  }
}

// ---------------- combine split-K partials -> ctx bf16 ----------------
__global__ __launch_bounds__(256) void attn_combine(const unsigned short* __restrict__ Opartb,
                                                    const float* __restrict__ ml,
                                                    unsigned short* __restrict__ ctxb) {
  const int w = threadIdx.x >> 6, lane = threadIdx.x & 63;
  const int row = blockIdx.x * 4 + w;     // 0 .. NN*HH-1
  const int q = row >> 3, head = row & 7;
  float ms[NSPLIT], ls[NSPLIT];
  float mglob = -1e30f;
  #pragma unroll
  for (int s = 0; s < NSPLIT; ++s) {
    size_t mb = ((size_t)(s*HH + head)*NN + q)*2;
    ms[s] = ml[mb]; ls[s] = ml[mb + 1];
    mglob = fmaxf(mglob, ms[s]);
  }
  float lt = 0.f, ov = 0.f;
  #pragma unroll
  for (int s = 0; s < NSPLIT; ++s) {
    float wgt = exp2f(ms[s] - mglob);
    lt += ls[s] * wgt;
    ov += bf2f(Opartb[((size_t)(s*HH + head)*NN + q)*64 + lane]) * wgt;
  }
  ctxb[(size_t)q*DD + head*64 + lane] = f2bf(ov / lt);
}

// ---------------- host ----------------
extern "C" void kernel_launch(void* const* d_in, const int* in_sizes, int n_in,
                              void* d_out, int out_size, void* d_ws, size_t ws_size,
                              hipStream_t stream) {
  const float* x       = (const float*)d_in[0];
  const int*   hidx    = (const int*)d_in[1];
  const float* hattr   = (const float*)d_in[2];
  const float* Wh      = (const float*)d_in[3];
  const float* att     = (const float*)d_in[4];
  const float* bias_h  = (const float*)d_in[5];
  const float* ln1_g   = (const float*)d_in[6];
  const float* ln1_b   = (const float*)d_in[7];
  const float* ln2_g   = (const float*)d_in[8];
  const float* ln2_b   = (const float*)d_in[9];
  const float* in_proj_w  = (const float*)d_in[10];
  const float* in_proj_b  = (const float*)d_in[11];
  const float* out_proj_w = (const float*)d_in[12];
  const float* out_proj_b = (const float*)d_in[13];
  const float* ff1_w   = (const float*)d_in[14];
  const float* ff1_b   = (const float*)d_in[15];
  const float* ff2_w   = (const float*)d_in[16];
  const float* ff2_b   = (const float*)d_in[17];
  const float* tln1_g  = (const float*)d_in[18];
  const float* tln1_b  = (const float*)d_in[19];
  const float* tln2_g  = (const float*)d_in[20];
  const float* tln2_b  = (const float*)d_in[21];
  const int* node_idx = hidx;
  const int* edge_idx = hidx + NNZC;

  char* ws = (char*)d_ws;
  size_t off = 0;
  auto alloc = [&](size_t bytes) -> void* {
    void* p = ws + off;
    off = (off + bytes + 63) & ~(size_t)63;
    return p;
  };
  float* s_node   = (float*)alloc(sizeof(float)*NN);
  float* s_edge   = (float*)alloc(sizeof(float)*MM);
  float* a_buf    = (float*)alloc(sizeof(float)*NNZC);
  float* amax     = (float*)alloc(sizeof(float)*NN);
  float* den      = (float*)alloc(sizeof(float)*NN);
  int*   DnCnt    = (int*)alloc(sizeof(int)*NN);
  int*   BnCnt    = (int*)alloc(sizeof(int)*MM);
  int*   node_off = (int*)alloc(sizeof(int)*(NN+1));
  int*   edge_off = (int*)alloc(sizeof(int)*(MM+1));
  int*   node_cur = (int*)alloc(sizeof(int)*NN);
  int*   edge_cur = (int*)alloc(sizeof(int)*MM);
  int*   node_list= (int*)alloc(sizeof(int)*NNZC);
  int*   edge_list= (int*)alloc(sizeof(int)*NNZC);
  float* x1       = (float*)alloc(sizeof(float)*NN*DD);
  float* x2       = (float*)alloc(sizeof(float)*NN*DD);
  unsigned short* xhb   = (unsigned short*)alloc(sizeof(unsigned short)*(NN+MM)*DD);  // [x; hattr]
  unsigned short* xelb  = (unsigned short*)alloc(sizeof(unsigned short)*(NN+MM)*DD);  // [xl; el]
  unsigned short* efb   = (unsigned short*)alloc(sizeof(unsigned short)*MM*DD);
  unsigned short* qkvbb = (unsigned short*)alloc(sizeof(unsigned short)*NN*3*DD);
  unsigned short* Vtb   = (unsigned short*)alloc(sizeof(unsigned short)*NN*DD);
  unsigned short* Whb   = (unsigned short*)alloc(sizeof(unsigned short)*DD*DD);
  unsigned short* ipwb  = (unsigned short*)alloc(sizeof(unsigned short)*3*DD*DD);
  unsigned short* opwb  = (unsigned short*)alloc(sizeof(unsigned short)*DD*DD);
  unsigned short* ff1wb = (unsigned short*)alloc(sizeof(unsigned short)*DFFC*DD);
  unsigned short* ff2wb = (unsigned short*)alloc(sizeof(unsigned short)*DD*DFFC);
  unsigned short* x1b   = (unsigned short*)alloc(sizeof(unsigned short)*NN*DD);
  unsigned short* x2b   = (unsigned short*)alloc(sizeof(unsigned short)*NN*DD);
  unsigned short* ctxb  = (unsigned short*)alloc(sizeof(unsigned short)*NN*DD);
  unsigned short* attn_outb = (unsigned short*)alloc(sizeof(unsigned short)*NN*DD);
  // "late" region: attention partials alias FFN-phase buffers (dead before ff1).
  // NSPLIT=8: Opartb 32 MB + mlb 2 MB = 34 MB; FFN phase uses first 20 MB.
  char* late = (char*)alloc(34u*1024*1024);
  unsigned short* Opartb = (unsigned short*)late;                        // 32 MB (attn phase)
  float*          mlb    = (float*)(late + 32u*1024*1024);               // 2 MB (attn phase)
  unsigned short* ffhb   = (unsigned short*)late;                        // 16 MB (FFN phase)
  unsigned short* ffob   = (unsigned short*)(late + 16u*1024*1024);      // 4 MB (FFN phase)
  unsigned short* xlb = xelb;
  unsigned short* elb = xelb + (size_t)NN*DD;
  (void)ws_size; (void)in_sizes; (void)n_in; (void)out_size;

  dim3 b256(256);
  // one-time bf16 conversions (single batched launch); x and hattr land adjacent in xhb
  f2b_multi<<<dim3(256, 7), b256, 0, stream>>>(
      x, xhb, NN*DD/8,  hattr, xhb + (size_t)NN*DD, MM*DD/8,  Wh, Whb, DD*DD/8,
      in_proj_w, ipwb, 3*DD*DD/8,  out_proj_w, opwb, DD*DD/8,
      ff1_w, ff1wb, DFFC*DD/8,  ff2_w, ff2wb, DD*DFFC/8);

  // [xl; el] = [x; hattr] @ Wh^T  (merged, BN=64: grid 40x8 = 320 blocks)
  gemm_bt_bf16_n64<<<dim3((NN+MM)/128, DD/64), b256, 0, stream>>>(xhb, Whb, nullptr, xelb, DD, DD, nullptr);
  // sparse hypergraph conv
  rowdot_both<<<(NN+MM)/4, b256, 0, stream>>>(xlb, elb, att, s_node, s_edge);
  init_kernel<<<NN/256, b256, 0, stream>>>(amax, den, DnCnt, BnCnt, node_cur, edge_cur);
  incidence_pass1<<<NNZC/256, b256, 0, stream>>>(node_idx, edge_idx, s_node, s_edge,
                                                 a_buf, amax, DnCnt, BnCnt);
  exscan2_kernel<<<2, 1024, 0, stream>>>(DnCnt, node_off, NN, BnCnt, edge_off, MM);
  incidence_pass2<<<NNZC/256, b256, 0, stream>>>(node_idx, edge_idx, a_buf, amax, den,
                                                 node_off, edge_off, node_cur, edge_cur,
                                                 node_list, edge_list);
  gather_edge<<<MM, b256, 0, stream>>>(edge_off, edge_list, node_idx, a_buf, den, xlb, efb);
  // gather_node + fused LN1 -> x1, x1b
  gather_node_ln<<<NN, b256, 0, stream>>>(node_off, node_list, edge_idx, a_buf, den, efb,
                                          bias_h, x, ln1_g, ln1_b, x1, x1b);
  // qkv (BN=64: grid 32x24 = 768 blocks; V-plane blocks write transposed Vtb directly)
  gemm_bt_bf16_n64<<<dim3(NN/128, (3*DD)/64), b256, 0, stream>>>(x1b, ipwb, in_proj_b, qkvbb, 3*DD, DD, Vtb);
  // attention (bf16 MFMA, split-K x8, KVBLK=64 + combine)
  attn_mfma_part<<<dim3(NN/64, HH, NSPLIT), b256, 0, stream>>>(qkvbb, Vtb, Opartb, mlb);
  attn_combine<<<NN*HH/4, b256, 0, stream>>>(Opartb, mlb, ctxb);
  // out_proj (BN=64: grid 32x8 = 256 blocks)
  gemm_bt_bf16_n64<<<dim3(NN/128, DD/64), b256, 0, stream>>>(ctxb, opwb, out_proj_b, attn_outb, DD, DD, nullptr);
  // x2 = LN(x1 + attn_out) (+ bf16)
  ln_residual<<<NN, b256, 0, stream>>>(x1, nullptr, attn_outb, tln1_g, tln1_b, x2, x2b);
  // ffn: ff1 (128x128 tile, grid 512; relu, bf16 out), ff2 (BN=64: grid 32x8 = 256, K=2048)
  gemm_bt_bf16<<<dim3(NN/128, DFFC/128), b256, 0, stream>>>(x2b, ff1wb, ff1_b, nullptr, ffhb, DFFC, DD, 1);
  gemm_bt_bf16_n64<<<dim3(NN/128, DD/64), b256, 0, stream>>>(ffhb, ff2wb, ff2_b, ffob, DD, DFFC, nullptr);
  // x3 = LN(x2 + ff); out = LN(x1 + x3)  (fused)
  ln_final2<<<NN, b256, 0, stream>>>(x2, ffob, x1, tln2_g, tln2_b, ln2_g, ln2_b, (float*)d_out);
}

// Round 15
// 264.406 us; speedup vs baseline: 1.0280x; 1.0280x over previous
//
#include <hip/hip_runtime.h>
#include <math.h>

#define NN   4096
#define MM   1024
#define NNZC 65536
#define DD   512
#define HH   8
#define DHH  64
#define DFFC 2048
#define NSPLIT 4

typedef short bf16x8 __attribute__((ext_vector_type(8)));
typedef float f32x4  __attribute__((ext_vector_type(4)));

static __device__ inline unsigned short f2bf(float f) {
  union { float f; unsigned int u; } v; v.f = f;
  unsigned int r = v.u + 0x7fff + ((v.u >> 16) & 1);   // RNE
  return (unsigned short)(r >> 16);
}
static __device__ inline float bf2f(unsigned short u) {
  return __uint_as_float((unsigned int)u << 16);
}

__device__ inline void gload16(const void* g, void* l) {
  __builtin_amdgcn_global_load_lds(
      (const __attribute__((address_space(1))) void*)g,
      (__attribute__((address_space(3))) void*)l, 16, 0, 0);
}

// ---------------- utility ----------------
__device__ inline void atomicMaxF(float* addr, float val) {
  if (val >= 0.f) atomicMax((int*)addr, __float_as_int(val));
  else            atomicMin((unsigned int*)addr, __float_as_uint(val));
}

// ---------------- init ----------------
__global__ void init_kernel(float* amax, float* den, int* DnCnt, int* BnCnt,
                            int* node_cur, int* edge_cur) {
  int i = blockIdx.x * 256 + threadIdx.x;
  if (i < NN) { amax[i] = -INFINITY; den[i] = 0.f; DnCnt[i] = 0; node_cur[i] = 0; }
  if (i < MM) { BnCnt[i] = 0; edge_cur[i] = 0; }
}

// ---------------- batched fp32 -> bf16 convert (7 segments, 1 launch) ----------------
__global__ __launch_bounds__(256) void f2b_multi(
    const float* s0, unsigned short* d0, int n0,
    const float* s1, unsigned short* d1, int n1,
    const float* s2, unsigned short* d2, int n2,
    const float* s3, unsigned short* d3, int n3,
    const float* s4, unsigned short* d4, int n4,
    const float* s5, unsigned short* d5, int n5,
    const float* s6, unsigned short* d6, int n6) {
  const float* in; unsigned short* out; int n8;
  switch (blockIdx.y) {
    case 0: in=s0; out=d0; n8=n0; break;
    case 1: in=s1; out=d1; n8=n1; break;
    case 2: in=s2; out=d2; n8=n2; break;
    case 3: in=s3; out=d3; n8=n3; break;
    case 4: in=s4; out=d4; n8=n4; break;
    case 5: in=s5; out=d5; n8=n5; break;
    default: in=s6; out=d6; n8=n6; break;
  }
  for (int i = blockIdx.x*256 + threadIdx.x; i < n8; i += gridDim.x*256) {
    float4 v0 = *(const float4*)&in[(size_t)i*8];
    float4 v1 = *(const float4*)&in[(size_t)i*8 + 4];
    unsigned short w[8];
    w[0]=f2bf(v0.x); w[1]=f2bf(v0.y); w[2]=f2bf(v0.z); w[3]=f2bf(v0.w);
    w[4]=f2bf(v1.x); w[5]=f2bf(v1.y); w[6]=f2bf(v1.z); w[7]=f2bf(v1.w);
    *(ulonglong2*)&out[(size_t)i*8] = *(ulonglong2*)w;
  }
}

// ---------------- bf16 MFMA NT GEMM, 128x128 tile (ff1) ----------------
__global__ __launch_bounds__(256) void gemm_bt_bf16(
    const unsigned short* __restrict__ A, const unsigned short* __restrict__ B,
    const float* __restrict__ bias, float* __restrict__ Cf,
    unsigned short* __restrict__ Cb, int N, int K, int relu) {
  __shared__ __align__(16) unsigned short Al[128*64];
  __shared__ __align__(16) unsigned short Bl[128*64];
  const int t = threadIdx.x;
  const int w = t >> 6, l = t & 63;
  const int lg = l >> 4, lid = l & 15;
  const int wr = w >> 1, wc = w & 1;
  const int bm = blockIdx.x * 128, bn = blockIdx.y * 128;

  f32x4 acc[4][4];
  #pragma unroll
  for (int mi = 0; mi < 4; ++mi)
    #pragma unroll
    for (int ni = 0; ni < 4; ++ni) acc[mi][ni] = (f32x4)0.f;

  for (int k0 = 0; k0 < K; k0 += 64) {
    #pragma unroll
    for (int i = 0; i < 4; ++i) {
      int cid = i*256 + t;
      int row = cid >> 3, cp = cid & 7;
      int gc = cp ^ (row & 7);
      gload16(&A[(size_t)(bm + row)*K + k0 + gc*8], &Al[cid*8]);
      gload16(&B[(size_t)(bn + row)*K + k0 + gc*8], &Bl[cid*8]);
    }
    asm volatile("s_waitcnt vmcnt(0)" ::: "memory");
    __syncthreads();
    #pragma unroll
    for (int ks = 0; ks < 2; ++ks) {
      bf16x8 af[4], bfr[4];
      #pragma unroll
      for (int mi = 0; mi < 4; ++mi) {
        int r = wr*64 + mi*16 + lid;
        af[mi] = *(const bf16x8*)&Al[r*64 + ((ks*4 + lg) ^ (r & 7))*8];
      }
      #pragma unroll
      for (int ni = 0; ni < 4; ++ni) {
        int r = wc*64 + ni*16 + lid;
        bfr[ni] = *(const bf16x8*)&Bl[r*64 + ((ks*4 + lg) ^ (r & 7))*8];
      }
      __builtin_amdgcn_s_setprio(1);
      #pragma unroll
      for (int mi = 0; mi < 4; ++mi)
        #pragma unroll
        for (int ni = 0; ni < 4; ++ni)
          acc[mi][ni] = __builtin_amdgcn_mfma_f32_16x16x32_bf16(af[mi], bfr[ni], acc[mi][ni], 0, 0, 0);
      __builtin_amdgcn_s_setprio(0);
    }
    __syncthreads();
  }

  #pragma unroll
  for (int ni = 0; ni < 4; ++ni) {
    int col = bn + wc*64 + ni*16 + lid;
    float bv = bias ? bias[col] : 0.f;
    #pragma unroll
    for (int mi = 0; mi < 4; ++mi) {
      #pragma unroll
      for (int rg = 0; rg < 4; ++rg) {
        int row = bm + wr*64 + mi*16 + lg*4 + rg;
        float v = acc[mi][ni][rg] + bv;
        if (relu) v = fmaxf(v, 0.f);
        if (Cf) Cf[(size_t)row*N + col] = v;
        if (Cb) Cb[(size_t)row*N + col] = f2bf(v);
      }
    }
  }
}

// ---------------- bf16 MFMA NT GEMM, 128x64 tile (small-N GEMMs) ----------------
// VtbOpt: if non-null and bn >= 1024 (V-plane of qkv), write the tile TRANSPOSED
// into Vtb[h][d][tok] instead of Cb (fuses conv_vt; identical rounding).
__global__ __launch_bounds__(256) void gemm_bt_bf16_n64(
    const unsigned short* __restrict__ A, const unsigned short* __restrict__ B,
    const float* __restrict__ bias, unsigned short* __restrict__ Cb, int N, int K,
    unsigned short* __restrict__ VtbOpt) {
  __shared__ __align__(16) unsigned short Al[128*64];
  __shared__ __align__(16) unsigned short Bl[64*64];
  const int t = threadIdx.x;
  const int w = t >> 6, l = t & 63;
  const int lg = l >> 4, lid = l & 15;
  const int wr = w >> 1, wc = w & 1;
  const int bm = blockIdx.x * 128, bn = blockIdx.y * 64;

  f32x4 acc[4][2];
  #pragma unroll
  for (int mi = 0; mi < 4; ++mi)
    #pragma unroll
    for (int ni = 0; ni < 2; ++ni) acc[mi][ni] = (f32x4)0.f;

  for (int k0 = 0; k0 < K; k0 += 64) {
    #pragma unroll
    for (int i = 0; i < 4; ++i) {
      int cid = i*256 + t;
      int row = cid >> 3, cp = cid & 7;
      int gc = cp ^ (row & 7);
      gload16(&A[(size_t)(bm + row)*K + k0 + gc*8], &Al[cid*8]);
    }
    #pragma unroll
    for (int i = 0; i < 2; ++i) {
      int cid = i*256 + t;
      int row = cid >> 3, cp = cid & 7;
      int gc = cp ^ (row & 7);
      gload16(&B[(size_t)(bn + row)*K + k0 + gc*8], &Bl[cid*8]);
    }
    asm volatile("s_waitcnt vmcnt(0)" ::: "memory");
    __syncthreads();
    #pragma unroll
    for (int ks = 0; ks < 2; ++ks) {
      bf16x8 af[4], bfr[2];
      #pragma unroll
      for (int mi = 0; mi < 4; ++mi) {
        int r = wr*64 + mi*16 + lid;
        af[mi] = *(const bf16x8*)&Al[r*64 + ((ks*4 + lg) ^ (r & 7))*8];
      }
      #pragma unroll
      for (int ni = 0; ni < 2; ++ni) {
        int r = wc*32 + ni*16 + lid;
        bfr[ni] = *(const bf16x8*)&Bl[r*64 + ((ks*4 + lg) ^ (r & 7))*8];
      }
      __builtin_amdgcn_s_setprio(1);
      #pragma unroll
      for (int mi = 0; mi < 4; ++mi)
        #pragma unroll
        for (int ni = 0; ni < 2; ++ni)
          acc[mi][ni] = __builtin_amdgcn_mfma_f32_16x16x32_bf16(af[mi], bfr[ni], acc[mi][ni], 0, 0, 0);
      __builtin_amdgcn_s_setprio(0);
    }
    __syncthreads();
  }

  if (VtbOpt && bn >= 1024) {
    #pragma unroll
    for (int ni = 0; ni < 2; ++ni) {
      int col = bn + wc*32 + ni*16 + lid;
      float bv = bias ? bias[col] : 0.f;
      int d = col - 1024;
      int h = d >> 6, dd = d & 63;
      #pragma unroll
      for (int mi = 0; mi < 4; ++mi) {
        int tok0 = bm + wr*64 + mi*16 + lg*4;
        ushort4 w4;
        w4.x = f2bf(acc[mi][ni][0] + bv);
        w4.y = f2bf(acc[mi][ni][1] + bv);
        w4.z = f2bf(acc[mi][ni][2] + bv);
        w4.w = f2bf(acc[mi][ni][3] + bv);
        *(ushort4*)&VtbOpt[(size_t)h*64*NN + (size_t)dd*NN + tok0] = w4;
      }
    }
  } else {
    #pragma unroll
    for (int ni = 0; ni < 2; ++ni) {
      int col = bn + wc*32 + ni*16 + lid;
      float bv = bias ? bias[col] : 0.f;
      #pragma unroll
      for (int mi = 0; mi < 4; ++mi) {
        #pragma unroll
        for (int rg = 0; rg < 4; ++rg) {
          int row = bm + wr*64 + mi*16 + lg*4 + rg;
          Cb[(size_t)row*N + col] = f2bf(acc[mi][ni][rg] + bv);
        }
      }
    }
  }
}

// ---------------- merged row dots ----------------
__global__ __launch_bounds__(256) void rowdot_both(const unsigned short* __restrict__ xlb,
    const unsigned short* __restrict__ elb, const float* __restrict__ att,
    float* __restrict__ s_node, float* __restrict__ s_edge) {
  int w = (blockIdx.x * 256 + threadIdx.x) >> 6;
  int lane = threadIdx.x & 63;
  const unsigned short* xr;
  const float* vec;
  if (w < NN) { xr = &xlb[(size_t)w * DD]; vec = att; }
  else        { xr = &elb[(size_t)(w - NN) * DD]; vec = att + DD; }
  float s = 0.f;
  #pragma unroll
  for (int j = 0; j < 8; ++j) s += bf2f(xr[lane + 64*j]) * vec[lane + 64*j];
  #pragma unroll
  for (int off = 1; off < 64; off <<= 1) s += __shfl_xor(s, off, 64);
  if (lane == 0) {
    if (w < NN) s_node[w] = s;
    else        s_edge[w - NN] = s;
  }
}

// ---------------- incidence pass 1 ----------------
__global__ void incidence_pass1(const int* __restrict__ node_idx, const int* __restrict__ edge_idx,
    const float* __restrict__ s_node, const float* __restrict__ s_edge,
    float* __restrict__ a_buf, float* amax, int* DnCnt, int* BnCnt) {
  int i = blockIdx.x * 256 + threadIdx.x;
  if (i >= NNZC) return;
  int n = node_idx[i], m = edge_idx[i];
  float a = s_node[n] + s_edge[m];
  a = (a >= 0.f) ? a : 0.2f * a;
  a_buf[i] = a;
  atomicMaxF(&amax[n], a);
  atomicAdd(&DnCnt[n], 1);
  atomicAdd(&BnCnt[m], 1);
}

// ---------------- dual exclusive scan ----------------
__global__ __launch_bounds__(1024) void exscan2_kernel(const int* __restrict__ inA,
    int* __restrict__ outA, int nA, const int* __restrict__ inB, int* __restrict__ outB, int nB) {
  const int* in; int* out; int n;
  if (blockIdx.x == 0) { in = inA; out = outA; n = nA; }
  else                 { in = inB; out = outB; n = nB; }
  __shared__ int sums[1024];
  const int t = threadIdx.x;
  const int chunk = (n + 1023) >> 10;
  const int start = t * chunk;
  const int stop  = min(start + chunk, n);
  int local = 0;
  for (int i = start; i < stop; ++i) local += in[i];
  sums[t] = local;
  __syncthreads();
  for (int o = 1; o < 1024; o <<= 1) {
    int v = (t >= o) ? sums[t - o] : 0;
    __syncthreads();
    sums[t] += v;
    __syncthreads();
  }
  int run = (t == 0) ? 0 : sums[t - 1];
  for (int i = start; i < stop; ++i) { out[i] = run; run += in[i]; }
  if (t == 1023) out[n] = sums[1023];
}

// ---------------- incidence pass 2 ----------------
__global__ void incidence_pass2(const int* __restrict__ node_idx, const int* __restrict__ edge_idx,
    float* __restrict__ a_buf, const float* __restrict__ amax, float* den,
    const int* __restrict__ node_off, const int* __restrict__ edge_off,
    int* node_cur, int* edge_cur, int* node_list, int* edge_list) {
  int i = blockIdx.x * 256 + threadIdx.x;
  if (i >= NNZC) return;
  int n = node_idx[i], m = edge_idx[i];
  float e = __expf(a_buf[i] - amax[n]);
  a_buf[i] = e;
  atomicAdd(&den[n], e);
  int pn = atomicAdd(&node_cur[n], 1);
  node_list[node_off[n] + pn] = i;
  int pm = atomicAdd(&edge_cur[m], 1);
  edge_list[edge_off[m] + pm] = i;
}

// ---------------- edge gather (bf16 xl in, bf16 ef out) ----------------
__global__ __launch_bounds__(256) void gather_edge(const int* __restrict__ edge_off,
    const int* __restrict__ edge_list, const int* __restrict__ node_idx,
    const float* __restrict__ a_buf, const float* __restrict__ den,
    const unsigned short* __restrict__ xlb, unsigned short* __restrict__ efb) {
  int m = blockIdx.x;
  int t = threadIdx.x;
  int beg = edge_off[m], end = edge_off[m+1];
  int cnt = end - beg;
  float Binv = (cnt > 0) ? (1.0f / (float)cnt) : 0.f;
  __shared__ int   ln_[128];
  __shared__ float lw_[128];
  float acc0 = 0.f, acc1 = 0.f;
  for (int c = beg; c < end; c += 128) {
    int nchunk = min(128, end - c);
    if (t < nchunk) {
      int i = edge_list[c + t];
      int n = node_idx[i];
      ln_[t] = n;
      lw_[t] = a_buf[i] / (den[n] + 1e-16f) * Binv;
    }
    __syncthreads();
    float a0 = 0.f, a1 = 0.f, b0 = 0.f, b1 = 0.f;
    int j = 0;
    for (; j + 1 < nchunk; j += 2) {
      float w0 = lw_[j], w1 = lw_[j+1];
      const unsigned short* r0 = &xlb[(size_t)ln_[j]   * DD];
      const unsigned short* r1 = &xlb[(size_t)ln_[j+1] * DD];
      a0 += w0 * bf2f(r0[t]);       b0 += w0 * bf2f(r0[t + 256]);
      a1 += w1 * bf2f(r1[t]);       b1 += w1 * bf2f(r1[t + 256]);
    }
    if (j < nchunk) {
      float w0 = lw_[j];
      const unsigned short* r0 = &xlb[(size_t)ln_[j] * DD];
      a0 += w0 * bf2f(r0[t]);       b0 += w0 * bf2f(r0[t + 256]);
    }
    acc0 += a0 + a1;
    acc1 += b0 + b1;
    __syncthreads();
  }
  efb[(size_t)m * DD + t]       = f2bf(acc0);
  efb[(size_t)m * DD + t + 256] = f2bf(acc1);
}

// ---------------- node gather + fused LN1: x1b = LN(x + conv) (bf16 out only) ----------
__global__ __launch_bounds__(256) void gather_node_ln(const int* __restrict__ node_off,
    const int* __restrict__ node_list, const int* __restrict__ edge_idx,
    const float* __restrict__ a_buf, const float* __restrict__ den,
    const unsigned short* __restrict__ efb, const float* __restrict__ bias_h,
    const float* __restrict__ x, const float* __restrict__ g, const float* __restrict__ be,
    unsigned short* __restrict__ x1b) {
  int n = blockIdx.x;
  int t = threadIdx.x;
  int beg = node_off[n], end = node_off[n+1];
  int cnt = end - beg;
  float Dinv = (cnt > 0) ? (1.0f / (float)cnt) : 0.f;
  float wscale = Dinv / (den[n] + 1e-16f);
  __shared__ int   le_[128];
  __shared__ float lw_[128];
  float acc0 = 0.f, acc1 = 0.f;
  for (int c = beg; c < end; c += 128) {
    int nchunk = min(128, end - c);
    if (t < nchunk) {
      int i = node_list[c + t];
      le_[t] = edge_idx[i];
      lw_[t] = a_buf[i] * wscale;
    }
    __syncthreads();
    float a0 = 0.f, a1 = 0.f, b0 = 0.f, b1 = 0.f;
    int j = 0;
    for (; j + 1 < nchunk; j += 2) {
      float w0 = lw_[j], w1 = lw_[j+1];
      const unsigned short* r0 = &efb[(size_t)le_[j]   * DD];
      const unsigned short* r1 = &efb[(size_t)le_[j+1] * DD];
      a0 += w0 * bf2f(r0[t]);       b0 += w0 * bf2f(r0[t + 256]);
      a1 += w1 * bf2f(r1[t]);       b1 += w1 * bf2f(r1[t + 256]);
    }
    if (j < nchunk) {
      float w0 = lw_[j];
      const unsigned short* r0 = &efb[(size_t)le_[j] * DD];
      a0 += w0 * bf2f(r0[t]);       b0 += w0 * bf2f(r0[t + 256]);
    }
    acc0 += a0 + a1;
    acc1 += b0 + b1;
    __syncthreads();
  }
  float v0 = x[(size_t)n*DD + t]       + acc0 + bias_h[t];
  float v1 = x[(size_t)n*DD + t + 256] + acc1 + bias_h[t + 256];
  __shared__ float red[4];
  __shared__ float mu_s, rstd_s;
  float s = v0 + v1;
  #pragma unroll
  for (int off = 1; off < 64; off <<= 1) s += __shfl_xor(s, off, 64);
  int wid = t >> 6;
  if ((t & 63) == 0) red[wid] = s;
  __syncthreads();
  if (t == 0) mu_s = (red[0] + red[1] + red[2] + red[3]) / 512.f;
  __syncthreads();
  float mu = mu_s;
  float d0 = v0 - mu, d1 = v1 - mu;
  float vs = d0*d0 + d1*d1;
  #pragma unroll
  for (int off = 1; off < 64; off <<= 1) vs += __shfl_xor(vs, off, 64);
  if ((t & 63) == 0) red[wid] = vs;
  __syncthreads();
  if (t == 0) rstd_s = rsqrtf((red[0] + red[1] + red[2] + red[3]) / 512.f + 1e-5f);
  __syncthreads();
  float rs = rstd_s;
  x1b[(size_t)n*DD + t]       = f2bf(d0 * rs * g[t]       + be[t]);
  x1b[(size_t)n*DD + t + 256] = f2bf(d1 * rs * g[t + 256] + be[t + 256]);
}

// ---------------- LN(a_bf16 + b_bf16) -> bf16 ----------------
__global__ __launch_bounds__(256) void ln_res_bb(const unsigned short* __restrict__ a,
    const unsigned short* __restrict__ b, const float* __restrict__ g,
    const float* __restrict__ be, unsigned short* __restrict__ outb) {
  int r = blockIdx.x;
  int t = threadIdx.x;
  float v0 = bf2f(a[(size_t)r*DD + t])       + bf2f(b[(size_t)r*DD + t]);
  float v1 = bf2f(a[(size_t)r*DD + t + 256]) + bf2f(b[(size_t)r*DD + t + 256]);
  __shared__ float red[4];
  __shared__ float mu_s, rstd_s;
  float s = v0 + v1;
  #pragma unroll
  for (int off = 1; off < 64; off <<= 1) s += __shfl_xor(s, off, 64);
  int wid = t >> 6;
  if ((t & 63) == 0) red[wid] = s;
  __syncthreads();
  if (t == 0) mu_s = (red[0] + red[1] + red[2] + red[3]) / 512.f;
  __syncthreads();
  float mu = mu_s;
  float d0 = v0 - mu, d1 = v1 - mu;
  float vs = d0*d0 + d1*d1;
  #pragma unroll
  for (int off = 1; off < 64; off <<= 1) vs += __shfl_xor(vs, off, 64);
  if ((t & 63) == 0) red[wid] = vs;
  __syncthreads();
  if (t == 0) rstd_s = rsqrtf((red[0] + red[1] + red[2] + red[3]) / 512.f + 1e-5f);
  __syncthreads();
  float rs = rstd_s;
  outb[(size_t)r*DD + t]       = f2bf(d0 * rs * g[t]       + be[t]);
  outb[(size_t)r*DD + t + 256] = f2bf(d1 * rs * g[t + 256] + be[t + 256]);
}

// ---------------- fused final 2 LayerNorms: x3=LN(x2b+ffob); out=LN(x1b+x3) ----------------
__global__ __launch_bounds__(256) void ln_final2(const unsigned short* __restrict__ x2b,
    const unsigned short* __restrict__ ffob, const unsigned short* __restrict__ x1b,
    const float* __restrict__ g1, const float* __restrict__ b1,
    const float* __restrict__ g2, const float* __restrict__ b2,
    float* __restrict__ out) {
  int r = blockIdx.x;
  int t = threadIdx.x;
  __shared__ float red[4];
  __shared__ float sh0, sh1;
  int wid = t >> 6;
  float v0 = bf2f(x2b[(size_t)r*DD + t])       + bf2f(ffob[(size_t)r*DD + t]);
  float v1 = bf2f(x2b[(size_t)r*DD + t + 256]) + bf2f(ffob[(size_t)r*DD + t + 256]);
  float s = v0 + v1;
  #pragma unroll
  for (int off = 1; off < 64; off <<= 1) s += __shfl_xor(s, off, 64);
  if ((t & 63) == 0) red[wid] = s;
  __syncthreads();
  if (t == 0) sh0 = (red[0] + red[1] + red[2] + red[3]) / 512.f;
  __syncthreads();
  float mu = sh0;
  float d0 = v0 - mu, d1 = v1 - mu;
  float vs = d0*d0 + d1*d1;
  #pragma unroll
  for (int off = 1; off < 64; off <<= 1) vs += __shfl_xor(vs, off, 64);
  if ((t & 63) == 0) red[wid] = vs;
  __syncthreads();
  if (t == 0) sh1 = rsqrtf((red[0] + red[1] + red[2] + red[3]) / 512.f + 1e-5f);
  __syncthreads();
  float rs = sh1;
  float x30 = d0 * rs * g1[t]       + b1[t];
  float x31 = d1 * rs * g1[t + 256] + b1[t + 256];
  __syncthreads();
  float u0 = bf2f(x1b[(size_t)r*DD + t])       + x30;
  float u1 = bf2f(x1b[(size_t)r*DD + t + 256]) + x31;
  s = u0 + u1;
  #pragma unroll
  for (int off = 1; off < 64; off <<= 1) s += __shfl_xor(s, off, 64);
  if ((t & 63) == 0) red[wid] = s;
  __syncthreads();
  if (t == 0) sh0 = (red[0] + red[1] + red[2] + red[3]) / 512.f;
  __syncthreads();
  mu = sh0;
  d0 = u0 - mu; d1 = u1 - mu;
  vs = d0*d0 + d1*d1;
  #pragma unroll
  for (int off = 1; off < 64; off <<= 1) vs += __shfl_xor(vs, off, 64);
  if ((t & 63) == 0) red[wid] = vs;
  __syncthreads();
  if (t == 0) sh1 = rsqrtf((red[0] + red[1] + red[2] + red[3]) / 512.f + 1e-5f);
  __syncthreads();
  rs = sh1;
  out[(size_t)r*DD + t]       = d0 * rs * g2[t]       + b2[t];
  out[(size_t)r*DD + t + 256] = d1 * rs * g2[t + 256] + b2[t + 256];
}

// ---------------- MFMA flash attention partial (split-K), KVBLK=64, swapped-QK^T ----
// Round-13 structure + hoisted LDS fragment addresses (loop-invariant, ~48 VALU/tile saved).
__global__ __launch_bounds__(256) void attn_mfma_part(const unsigned short* __restrict__ qkvbb,
                                                      const unsigned short* __restrict__ Vtb,
                                                      unsigned short* __restrict__ Opartb,
                                                      float* __restrict__ ml) {
  const int head = blockIdx.y;
  const int z = blockIdx.z;
  const int q0 = blockIdx.x * 64;
  const int t = threadIdx.x;
  const int w = t >> 6;
  const int l = t & 63;
  const int lg = l >> 4;
  const int lid = l & 15;
  const float sc = 0.125f * 1.44269504f;    // 1/sqrt(64) * log2(e)
  const float THRraw = 44.36f;              // 8 / sc

  __shared__ __align__(16) unsigned short Kl[64*64];
  __shared__ __align__(16) unsigned short Vl[64*64];

  bf16x8 qa[2];
  {
    const int qrow = q0 + w*16 + lid;
    const unsigned short* qp = &qkvbb[(size_t)qrow*1536 + head*64];
    qa[0] = *(const bf16x8*)&qp[lg*8];
    qa[1] = *(const bf16x8*)&qp[32 + lg*8];
  }

  // hoisted fragment addresses: addr[i][hf] for row = i*16+lid (same formula for K and V)
  int addr[4][2];
  #pragma unroll
  for (int i = 0; i < 4; ++i)
    #pragma unroll
    for (int hf = 0; hf < 2; ++hf) {
      int row = i*16 + lid;
      addr[i][hf] = (row*64 + hf*32 + lg*8) ^ ((row & 7) << 3);
    }

  float m = -1e30f, msc = -1e30f, lsum = 0.f;
  f32x4 o[4];
  #pragma unroll
  for (int dt = 0; dt < 4; ++dt) o[dt] = (f32x4)0.f;

  const unsigned short* Kh = qkvbb + 512 + head*64;          // row stride 1536
  const unsigned short* Vh = Vtb + (size_t)head*64*NN;
  const int kt0 = z * (NN / NSPLIT);
  const int kt1 = kt0 + (NN / NSPLIT);

  const int srow0 = t >> 3,        scc = (t & 7) * 8;
  const int srow1 = 32 + (t >> 3);
  const int sdst0 = (srow0*64 + scc) ^ ((srow0 & 7) << 3);
  const int sdst1 = (srow1*64 + scc) ^ ((srow1 & 7) << 3);
  const int kperm0 = 8*((srow0>>2)&3) + 4*((srow0>>4)&1) + (srow0&3) + 32*(srow0>>5);
  const int kperm1 = 8*((srow1>>2)&3) + 4*((srow1>>4)&1) + (srow1&3) + 32*(srow1>>5);
  ulonglong2 kreg0, kreg1, vreg0, vreg1;

#define LOADKV(ktv) do { \
    kreg0 = *(const ulonglong2*)&Kh[(size_t)((ktv) + kperm0)*1536 + scc]; \
    vreg0 = *(const ulonglong2*)&Vh[(size_t)srow0*NN + (ktv) + scc]; \
    kreg1 = *(const ulonglong2*)&Kh[(size_t)((ktv) + kperm1)*1536 + scc]; \
    vreg1 = *(const ulonglong2*)&Vh[(size_t)srow1*NN + (ktv) + scc]; \
  } while (0)
#define STORKV() do { \
    *(ulonglong2*)&Kl[sdst0] = kreg0; *(ulonglong2*)&Vl[sdst0] = vreg0; \
    *(ulonglong2*)&Kl[sdst1] = kreg1; *(ulonglong2*)&Vl[sdst1] = vreg1; \
  } while (0)

  LOADKV(kt0);
  STORKV();
  __syncthreads();

  for (int kt = kt0; kt < kt1; kt += 64) {
    const bool hn = (kt + 64) < kt1;
    if (hn) LOADKV(kt + 64);   // issue early; lands during compute (T14)

    // ---- S^T = K Q^T (swapped operands) ----
    f32x4 s[4];
    #pragma unroll
    for (int n = 0; n < 4; ++n) s[n] = (f32x4)0.f;
    __builtin_amdgcn_s_setprio(1);
    #pragma unroll
    for (int n = 0; n < 4; ++n) {
      #pragma unroll
      for (int hf = 0; hf < 2; ++hf) {
        bf16x8 kb = *(const bf16x8*)&Kl[addr[n][hf]];
        s[n] = __builtin_amdgcn_mfma_f32_16x16x32_bf16(kb, qa[hf], s[n], 0, 0, 0);
      }
    }
    __builtin_amdgcn_s_setprio(0);

    // ---- in-register online softmax, raw units (q = lid per lane) ----
    float a0 = fmaxf(fmaxf(s[0][0], s[0][1]), s[0][2]);
    float a1 = fmaxf(fmaxf(s[0][3], s[1][0]), s[1][1]);
    float a2 = fmaxf(fmaxf(s[1][2], s[1][3]), s[2][0]);
    float a3 = fmaxf(fmaxf(s[2][1], s[2][2]), s[2][3]);
    float a4 = fmaxf(fmaxf(s[3][0], s[3][1]), s[3][2]);
    float mx = fmaxf(fmaxf(fmaxf(a0, a1), a2), fmaxf(fmaxf(a3, a4), s[3][3]));
    mx = fmaxf(mx, __shfl_xor(mx, 16, 64));
    mx = fmaxf(mx, __shfl_xor(mx, 32, 64));
    if (!__all(mx <= m + THRraw)) {
      float mn = fmaxf(m, mx);
      float c = exp2f((m - mn) * sc);
      m = mn;
      msc = m * sc;
      lsum *= c;
      #pragma unroll
      for (int r = 0; r < 4; ++r) {
        float cr = __shfl(c, lg*4 + r, 64);
        #pragma unroll
        for (int dt = 0; dt < 4; ++dt) o[dt][r] *= cr;
      }
    }
    float ps = 0.f;
    #pragma unroll
    for (int n = 0; n < 4; ++n)
      #pragma unroll
      for (int r = 0; r < 4; ++r) {
        float p = exp2f(fmaf(s[n][r], sc, -msc));
        s[n][r] = p;
        ps += p;
      }
    ps += __shfl_xor(ps, 16, 64);
    ps += __shfl_xor(ps, 32, 64);
    lsum += ps;

    // ---- P repack: fully in-lane (thanks to K row permutation) ----
    union { bf16x8 v; unsigned int u[4]; } pa[2];
    #pragma unroll
    for (int hf = 0; hf < 2; ++hf) {
      asm("v_cvt_pk_bf16_f32 %0, %1, %2" : "=v"(pa[hf].u[0]) : "v"(s[2*hf][0]),   "v"(s[2*hf][1]));
      asm("v_cvt_pk_bf16_f32 %0, %1, %2" : "=v"(pa[hf].u[1]) : "v"(s[2*hf][2]),   "v"(s[2*hf][3]));
      asm("v_cvt_pk_bf16_f32 %0, %1, %2" : "=v"(pa[hf].u[2]) : "v"(s[2*hf+1][0]), "v"(s[2*hf+1][1]));
      asm("v_cvt_pk_bf16_f32 %0, %1, %2" : "=v"(pa[hf].u[3]) : "v"(s[2*hf+1][2]), "v"(s[2*hf+1][3]));
    }

    // ---- O += P V ----
    __builtin_amdgcn_s_setprio(1);
    #pragma unroll
    for (int dt = 0; dt < 4; ++dt) {
      #pragma unroll
      for (int hf = 0; hf < 2; ++hf) {
        bf16x8 vb = *(const bf16x8*)&Vl[addr[dt][hf]];
        o[dt] = __builtin_amdgcn_mfma_f32_16x16x32_bf16(pa[hf].v, vb, o[dt], 0, 0, 0);
      }
    }
    __builtin_amdgcn_s_setprio(0);

    __syncthreads();           // all waves done reading Kl/Vl
    if (hn) {
      STORKV();                // write prefetched tile
      __syncthreads();
    }
  }
#undef LOADKV
#undef STORKV

  // ---- epilogue: bf16 partial O (rows q=lg*4+r) + per-lane (msc, l) for q=lid ----
  #pragma unroll
  for (int r = 0; r < 4; ++r) {
    int q = q0 + w*16 + lg*4 + r;
    size_t base = ((size_t)(z*HH + head)*NN + q)*64;
    #pragma unroll
    for (int dt = 0; dt < 4; ++dt)
      Opartb[base + dt*16 + lid] = f2bf(o[dt][r]);
  }
  if (l < 16) {
    int q = q0 + w*16 + l;
    size_t mb = ((size_t)(z*HH + head)*NN + q)*2;
    ml[mb]     = msc;
    ml[mb + 1] = lsum;
  }
}

// ---------------- combine split-K partials -> ctx bf16 ----------------
__global__ __launch_bounds__(256) void attn_combine(const unsigned short* __restrict__ Opartb,
                                                    const float* __restrict__ ml,
                                                    unsigned short* __restrict__ ctxb) {
  const int w = threadIdx.x >> 6, lane = threadIdx.x & 63;
  const int row = blockIdx.x * 4 + w;     // 0 .. NN*HH-1
  const int q = row >> 3, head = row & 7;
  float ms[NSPLIT], ls[NSPLIT];
  float mglob = -1e30f;
  #pragma unroll
  for (int s = 0; s < NSPLIT; ++s) {
    size_t mb = ((size_t)(s*HH + head)*NN + q)*2;
    ms[s] = ml[mb]; ls[s] = ml[mb + 1];
    mglob = fmaxf(mglob, ms[s]);
  }
  float lt = 0.f, ov = 0.f;
  #pragma unroll
  for (int s = 0; s < NSPLIT; ++s) {
    float wgt = exp2f(ms[s] - mglob);
    lt += ls[s] * wgt;
    ov += bf2f(Opartb[((size_t)(s*HH + head)*NN + q)*64 + lane]) * wgt;
  }
  ctxb[(size_t)q*DD + head*64 + lane] = f2bf(ov / lt);
}

// ---------------- host ----------------
extern "C" void kernel_launch(void* const* d_in, const int* in_sizes, int n_in,
                              void* d_out, int out_size, void* d_ws, size_t ws_size,
                              hipStream_t stream) {
  const float* x       = (const float*)d_in[0];
  const int*   hidx    = (const int*)d_in[1];
  const float* hattr   = (const float*)d_in[2];
  const float* Wh      = (const float*)d_in[3];
  const float* att     = (const float*)d_in[4];
  const float* bias_h  = (const float*)d_in[5];
  const float* ln1_g   = (const float*)d_in[6];
  const float* ln1_b   = (const float*)d_in[7];
  const float* ln2_g   = (const float*)d_in[8];
  const float* ln2_b   = (const float*)d_in[9];
  const float* in_proj_w  = (const float*)d_in[10];
  const float* in_proj_b  = (const float*)d_in[11];
  const float* out_proj_w = (const float*)d_in[12];
  const float* out_proj_b = (const float*)d_in[13];
  const float* ff1_w   = (const float*)d_in[14];
  const float* ff1_b   = (const float*)d_in[15];
  const float* ff2_w   = (const float*)d_in[16];
  const float* ff2_b   = (const float*)d_in[17];
  const float* tln1_g  = (const float*)d_in[18];
  const float* tln1_b  = (const float*)d_in[19];
  const float* tln2_g  = (const float*)d_in[20];
  const float* tln2_b  = (const float*)d_in[21];
  const int* node_idx = hidx;
  const int* edge_idx = hidx + NNZC;

  char* ws = (char*)d_ws;
  size_t off = 0;
  auto alloc = [&](size_t bytes) -> void* {
    void* p = ws + off;
    off = (off + bytes + 63) & ~(size_t)63;
    return p;
  };
  float* s_node   = (float*)alloc(sizeof(float)*NN);
  float* s_edge   = (float*)alloc(sizeof(float)*MM);
  float* a_buf    = (float*)alloc(sizeof(float)*NNZC);
  float* amax     = (float*)alloc(sizeof(float)*NN);
  float* den      = (float*)alloc(sizeof(float)*NN);
  int*   DnCnt    = (int*)alloc(sizeof(int)*NN);
  int*   BnCnt    = (int*)alloc(sizeof(int)*MM);
  int*   node_off = (int*)alloc(sizeof(int)*(NN+1));
  int*   edge_off = (int*)alloc(sizeof(int)*(MM+1));
  int*   node_cur = (int*)alloc(sizeof(int)*NN);
  int*   edge_cur = (int*)alloc(sizeof(int)*MM);
  int*   node_list= (int*)alloc(sizeof(int)*NNZC);
  int*   edge_list= (int*)alloc(sizeof(int)*NNZC);
  unsigned short* xhb   = (unsigned short*)alloc(sizeof(unsigned short)*(NN+MM)*DD);  // [x; hattr]
  unsigned short* xelb  = (unsigned short*)alloc(sizeof(unsigned short)*(NN+MM)*DD);  // [xl; el]
  unsigned short* efb   = (unsigned short*)alloc(sizeof(unsigned short)*MM*DD);
  unsigned short* qkvbb = (unsigned short*)alloc(sizeof(unsigned short)*NN*3*DD);
  unsigned short* Vtb   = (unsigned short*)alloc(sizeof(unsigned short)*NN*DD);
  unsigned short* Whb   = (unsigned short*)alloc(sizeof(unsigned short)*DD*DD);
  unsigned short* ipwb  = (unsigned short*)alloc(sizeof(unsigned short)*3*DD*DD);
  unsigned short* opwb  = (unsigned short*)alloc(sizeof(unsigned short)*DD*DD);
  unsigned short* ff1wb = (unsigned short*)alloc(sizeof(unsigned short)*DFFC*DD);
  unsigned short* ff2wb = (unsigned short*)alloc(sizeof(unsigned short)*DD*DFFC);
  unsigned short* x1b   = (unsigned short*)alloc(sizeof(unsigned short)*NN*DD);
  unsigned short* x2b   = (unsigned short*)alloc(sizeof(unsigned short)*NN*DD);
  unsigned short* ctxb  = (unsigned short*)alloc(sizeof(unsigned short)*NN*DD);
  unsigned short* attn_outb = (unsigned short*)alloc(sizeof(unsigned short)*NN*DD);
  // "late" region: attention partials alias FFN-phase buffers (dead before ff1).
  char* late = (char*)alloc(20u*1024*1024);
  unsigned short* Opartb = (unsigned short*)late;                        // 16 MB (attn phase)
  float*          mlb    = (float*)(late + 16u*1024*1024);               // 1 MB (attn phase)
  unsigned short* ffhb   = (unsigned short*)late;                        // 16 MB (FFN phase)
  unsigned short* ffob   = (unsigned short*)(late + 16u*1024*1024);      // 4 MB (FFN phase)
  unsigned short* xlb = xelb;
  unsigned short* elb = xelb + (size_t)NN*DD;
  (void)ws_size; (void)in_sizes; (void)n_in; (void)out_size;

  dim3 b256(256);
  // one-time bf16 conversions (single batched launch); x and hattr land adjacent in xhb
  f2b_multi<<<dim3(256, 7), b256, 0, stream>>>(
      x, xhb, NN*DD/8,  hattr, xhb + (size_t)NN*DD, MM*DD/8,  Wh, Whb, DD*DD/8,
      in_proj_w, ipwb, 3*DD*DD/8,  out_proj_w, opwb, DD*DD/8,
      ff1_w, ff1wb, DFFC*DD/8,  ff2_w, ff2wb, DD*DFFC/8);

  // [xl; el] = [x; hattr] @ Wh^T  (merged, BN=64)
  gemm_bt_bf16_n64<<<dim3((NN+MM)/128, DD/64), b256, 0, stream>>>(xhb, Whb, nullptr, xelb, DD, DD, nullptr);
  // sparse hypergraph conv
  rowdot_both<<<(NN+MM)/4, b256, 0, stream>>>(xlb, elb, att, s_node, s_edge);
  init_kernel<<<NN/256, b256, 0, stream>>>(amax, den, DnCnt, BnCnt, node_cur, edge_cur);
  incidence_pass1<<<NNZC/256, b256, 0, stream>>>(node_idx, edge_idx, s_node, s_edge,
                                                 a_buf, amax, DnCnt, BnCnt);
  exscan2_kernel<<<2, 1024, 0, stream>>>(DnCnt, node_off, NN, BnCnt, edge_off, MM);
  incidence_pass2<<<NNZC/256, b256, 0, stream>>>(node_idx, edge_idx, a_buf, amax, den,
                                                 node_off, edge_off, node_cur, edge_cur,
                                                 node_list, edge_list);
  gather_edge<<<MM, b256, 0, stream>>>(edge_off, edge_list, node_idx, a_buf, den, xlb, efb);
  // gather_node + fused LN1 -> x1b (bf16 residual stream)
  gather_node_ln<<<NN, b256, 0, stream>>>(node_off, node_list, edge_idx, a_buf, den, efb,
                                          bias_h, x, ln1_g, ln1_b, x1b);
  // qkv (BN=64; V-plane blocks write transposed Vtb directly)
  gemm_bt_bf16_n64<<<dim3(NN/128, (3*DD)/64), b256, 0, stream>>>(x1b, ipwb, in_proj_b, qkvbb, 3*DD, DD, Vtb);
  // attention (bf16 MFMA, split-K x4, KVBLK=64 + combine)
  attn_mfma_part<<<dim3(NN/64, HH, NSPLIT), b256, 0, stream>>>(qkvbb, Vtb, Opartb, mlb);
  attn_combine<<<NN*HH/4, b256, 0, stream>>>(Opartb, mlb, ctxb);
  // out_proj (BN=64)
  gemm_bt_bf16_n64<<<dim3(NN/128, DD/64), b256, 0, stream>>>(ctxb, opwb, out_proj_b, attn_outb, DD, DD, nullptr);
  // x2b = LN(x1b + attn_outb)
  ln_res_bb<<<NN, b256, 0, stream>>>(x1b, attn_outb, tln1_g, tln1_b, x2b);
  // ffn: ff1 (128x128 tile; relu, bf16 out), ff2 (BN=64, K=2048)
  gemm_bt_bf16<<<dim3(NN/128, DFFC/128), b256, 0, stream>>>(x2b, ff1wb, ff1_b, nullptr, ffhb, DFFC, DD, 1);
  gemm_bt_bf16_n64<<<dim3(NN/128, DD/64), b256, 0, stream>>>(ffhb, ff2wb, ff2_b, ffob, DD, DFFC, nullptr);
  // x3 = LN(x2b + ffob); out = LN(x1b + x3)  (fused)
  ln_final2<<<NN, b256, 0, stream>>>(x2b, ffob, x1b, tln2_g, tln2_b, ln2_g, ln2_b, (float*)d_out);
}

// Round 16
// 260.314 us; speedup vs baseline: 1.0441x; 1.0157x over previous
//
#include <hip/hip_runtime.h>
#include <math.h>

#define NN   4096
#define MM   1024
#define NNZC 65536
#define DD   512
#define HH   8
#define DHH  64
#define DFFC 2048
#define NSPLIT 4

typedef short bf16x8 __attribute__((ext_vector_type(8)));
typedef float f32x4  __attribute__((ext_vector_type(4)));

static __device__ inline unsigned short f2bf(float f) {
  union { float f; unsigned int u; } v; v.f = f;
  unsigned int r = v.u + 0x7fff + ((v.u >> 16) & 1);   // RNE
  return (unsigned short)(r >> 16);
}
static __device__ inline float bf2f(unsigned short u) {
  return __uint_as_float((unsigned int)u << 16);
}

__device__ inline void gload16(const void* g, void* l) {
  __builtin_amdgcn_global_load_lds(
      (const __attribute__((address_space(1))) void*)g,
      (__attribute__((address_space(3))) void*)l, 16, 0, 0);
}

// ---------------- utility ----------------
__device__ inline void atomicMaxF(float* addr, float val) {
  if (val >= 0.f) atomicMax((int*)addr, __float_as_int(val));
  else            atomicMin((unsigned int*)addr, __float_as_uint(val));
}

// ---------------- init ----------------
__global__ void init_kernel(float* amax, float* den, int* DnCnt, int* BnCnt,
                            int* node_cur, int* edge_cur) {
  int i = blockIdx.x * 256 + threadIdx.x;
  if (i < NN) { amax[i] = -INFINITY; den[i] = 0.f; DnCnt[i] = 0; node_cur[i] = 0; }
  if (i < MM) { BnCnt[i] = 0; edge_cur[i] = 0; }
}

// ---------------- batched fp32 -> bf16 convert (7 segments, 1 launch) ----------------
__global__ __launch_bounds__(256) void f2b_multi(
    const float* s0, unsigned short* d0, int n0,
    const float* s1, unsigned short* d1, int n1,
    const float* s2, unsigned short* d2, int n2,
    const float* s3, unsigned short* d3, int n3,
    const float* s4, unsigned short* d4, int n4,
    const float* s5, unsigned short* d5, int n5,
    const float* s6, unsigned short* d6, int n6) {
  const float* in; unsigned short* out; int n8;
  switch (blockIdx.y) {
    case 0: in=s0; out=d0; n8=n0; break;
    case 1: in=s1; out=d1; n8=n1; break;
    case 2: in=s2; out=d2; n8=n2; break;
    case 3: in=s3; out=d3; n8=n3; break;
    case 4: in=s4; out=d4; n8=n4; break;
    case 5: in=s5; out=d5; n8=n5; break;
    default: in=s6; out=d6; n8=n6; break;
  }
  for (int i = blockIdx.x*256 + threadIdx.x; i < n8; i += gridDim.x*256) {
    float4 v0 = *(const float4*)&in[(size_t)i*8];
    float4 v1 = *(const float4*)&in[(size_t)i*8 + 4];
    unsigned short w[8];
    w[0]=f2bf(v0.x); w[1]=f2bf(v0.y); w[2]=f2bf(v0.z); w[3]=f2bf(v0.w);
    w[4]=f2bf(v1.x); w[5]=f2bf(v1.y); w[6]=f2bf(v1.z); w[7]=f2bf(v1.w);
    *(ulonglong2*)&out[(size_t)i*8] = *(ulonglong2*)w;
  }
}

// ---------------- bf16 MFMA NT GEMM, 128x128 tile (ff1) ----------------
__global__ __launch_bounds__(256) void gemm_bt_bf16(
    const unsigned short* __restrict__ A, const unsigned short* __restrict__ B,
    const float* __restrict__ bias, float* __restrict__ Cf,
    unsigned short* __restrict__ Cb, int N, int K, int relu) {
  __shared__ __align__(16) unsigned short Al[128*64];
  __shared__ __align__(16) unsigned short Bl[128*64];
  const int t = threadIdx.x;
  const int w = t >> 6, l = t & 63;
  const int lg = l >> 4, lid = l & 15;
  const int wr = w >> 1, wc = w & 1;
  const int bm = blockIdx.x * 128, bn = blockIdx.y * 128;

  f32x4 acc[4][4];
  #pragma unroll
  for (int mi = 0; mi < 4; ++mi)
    #pragma unroll
    for (int ni = 0; ni < 4; ++ni) acc[mi][ni] = (f32x4)0.f;

  for (int k0 = 0; k0 < K; k0 += 64) {
    #pragma unroll
    for (int i = 0; i < 4; ++i) {
      int cid = i*256 + t;
      int row = cid >> 3, cp = cid & 7;
      int gc = cp ^ (row & 7);
      gload16(&A[(size_t)(bm + row)*K + k0 + gc*8], &Al[cid*8]);
      gload16(&B[(size_t)(bn + row)*K + k0 + gc*8], &Bl[cid*8]);
    }
    asm volatile("s_waitcnt vmcnt(0)" ::: "memory");
    __syncthreads();
    #pragma unroll
    for (int ks = 0; ks < 2; ++ks) {
      bf16x8 af[4], bfr[4];
      #pragma unroll
      for (int mi = 0; mi < 4; ++mi) {
        int r = wr*64 + mi*16 + lid;
        af[mi] = *(const bf16x8*)&Al[r*64 + ((ks*4 + lg) ^ (r & 7))*8];
      }
      #pragma unroll
      for (int ni = 0; ni < 4; ++ni) {
        int r = wc*64 + ni*16 + lid;
        bfr[ni] = *(const bf16x8*)&Bl[r*64 + ((ks*4 + lg) ^ (r & 7))*8];
      }
      __builtin_amdgcn_s_setprio(1);
      #pragma unroll
      for (int mi = 0; mi < 4; ++mi)
        #pragma unroll
        for (int ni = 0; ni < 4; ++ni)
          acc[mi][ni] = __builtin_amdgcn_mfma_f32_16x16x32_bf16(af[mi], bfr[ni], acc[mi][ni], 0, 0, 0);
      __builtin_amdgcn_s_setprio(0);
    }
    __syncthreads();
  }

  #pragma unroll
  for (int ni = 0; ni < 4; ++ni) {
    int col = bn + wc*64 + ni*16 + lid;
    float bv = bias ? bias[col] : 0.f;
    #pragma unroll
    for (int mi = 0; mi < 4; ++mi) {
      #pragma unroll
      for (int rg = 0; rg < 4; ++rg) {
        int row = bm + wr*64 + mi*16 + lg*4 + rg;
        float v = acc[mi][ni][rg] + bv;
        if (relu) v = fmaxf(v, 0.f);
        if (Cf) Cf[(size_t)row*N + col] = v;
        if (Cb) Cb[(size_t)row*N + col] = f2bf(v);
      }
    }
  }
}

// ---------------- bf16 MFMA NT GEMM, 128x64 tile (small-N GEMMs) ----------------
__global__ __launch_bounds__(256) void gemm_bt_bf16_n64(
    const unsigned short* __restrict__ A, const unsigned short* __restrict__ B,
    const float* __restrict__ bias, unsigned short* __restrict__ Cb, int N, int K,
    unsigned short* __restrict__ VtbOpt) {
  __shared__ __align__(16) unsigned short Al[128*64];
  __shared__ __align__(16) unsigned short Bl[64*64];
  const int t = threadIdx.x;
  const int w = t >> 6, l = t & 63;
  const int lg = l >> 4, lid = l & 15;
  const int wr = w >> 1, wc = w & 1;
  const int bm = blockIdx.x * 128, bn = blockIdx.y * 64;

  f32x4 acc[4][2];
  #pragma unroll
  for (int mi = 0; mi < 4; ++mi)
    #pragma unroll
    for (int ni = 0; ni < 2; ++ni) acc[mi][ni] = (f32x4)0.f;

  for (int k0 = 0; k0 < K; k0 += 64) {
    #pragma unroll
    for (int i = 0; i < 4; ++i) {
      int cid = i*256 + t;
      int row = cid >> 3, cp = cid & 7;
      int gc = cp ^ (row & 7);
      gload16(&A[(size_t)(bm + row)*K + k0 + gc*8], &Al[cid*8]);
    }
    #pragma unroll
    for (int i = 0; i < 2; ++i) {
      int cid = i*256 + t;
      int row = cid >> 3, cp = cid & 7;
      int gc = cp ^ (row & 7);
      gload16(&B[(size_t)(bn + row)*K + k0 + gc*8], &Bl[cid*8]);
    }
    asm volatile("s_waitcnt vmcnt(0)" ::: "memory");
    __syncthreads();
    #pragma unroll
    for (int ks = 0; ks < 2; ++ks) {
      bf16x8 af[4], bfr[2];
      #pragma unroll
      for (int mi = 0; mi < 4; ++mi) {
        int r = wr*64 + mi*16 + lid;
        af[mi] = *(const bf16x8*)&Al[r*64 + ((ks*4 + lg) ^ (r & 7))*8];
      }
      #pragma unroll
      for (int ni = 0; ni < 2; ++ni) {
        int r = wc*32 + ni*16 + lid;
        bfr[ni] = *(const bf16x8*)&Bl[r*64 + ((ks*4 + lg) ^ (r & 7))*8];
      }
      __builtin_amdgcn_s_setprio(1);
      #pragma unroll
      for (int mi = 0; mi < 4; ++mi)
        #pragma unroll
        for (int ni = 0; ni < 2; ++ni)
          acc[mi][ni] = __builtin_amdgcn_mfma_f32_16x16x32_bf16(af[mi], bfr[ni], acc[mi][ni], 0, 0, 0);
      __builtin_amdgcn_s_setprio(0);
    }
    __syncthreads();
  }

  if (VtbOpt && bn >= 1024) {
    #pragma unroll
    for (int ni = 0; ni < 2; ++ni) {
      int col = bn + wc*32 + ni*16 + lid;
      float bv = bias ? bias[col] : 0.f;
      int d = col - 1024;
      int h = d >> 6, dd = d & 63;
      #pragma unroll
      for (int mi = 0; mi < 4; ++mi) {
        int tok0 = bm + wr*64 + mi*16 + lg*4;
        ushort4 w4;
        w4.x = f2bf(acc[mi][ni][0] + bv);
        w4.y = f2bf(acc[mi][ni][1] + bv);
        w4.z = f2bf(acc[mi][ni][2] + bv);
        w4.w = f2bf(acc[mi][ni][3] + bv);
        *(ushort4*)&VtbOpt[(size_t)h*64*NN + (size_t)dd*NN + tok0] = w4;
      }
    }
  } else {
    #pragma unroll
    for (int ni = 0; ni < 2; ++ni) {
      int col = bn + wc*32 + ni*16 + lid;
      float bv = bias ? bias[col] : 0.f;
      #pragma unroll
      for (int mi = 0; mi < 4; ++mi) {
        #pragma unroll
        for (int rg = 0; rg < 4; ++rg) {
          int row = bm + wr*64 + mi*16 + lg*4 + rg;
          Cb[(size_t)row*N + col] = f2bf(acc[mi][ni][rg] + bv);
        }
      }
    }
  }
}

// ---------------- merged row dots ----------------
__global__ __launch_bounds__(256) void rowdot_both(const unsigned short* __restrict__ xlb,
    const unsigned short* __restrict__ elb, const float* __restrict__ att,
    float* __restrict__ s_node, float* __restrict__ s_edge) {
  int w = (blockIdx.x * 256 + threadIdx.x) >> 6;
  int lane = threadIdx.x & 63;
  const unsigned short* xr;
  const float* vec;
  if (w < NN) { xr = &xlb[(size_t)w * DD]; vec = att; }
  else        { xr = &elb[(size_t)(w - NN) * DD]; vec = att + DD; }
  float s = 0.f;
  #pragma unroll
  for (int j = 0; j < 8; ++j) s += bf2f(xr[lane + 64*j]) * vec[lane + 64*j];
  #pragma unroll
  for (int off = 1; off < 64; off <<= 1) s += __shfl_xor(s, off, 64);
  if (lane == 0) {
    if (w < NN) s_node[w] = s;
    else        s_edge[w - NN] = s;
  }
}

// ---------------- incidence pass 1 ----------------
__global__ void incidence_pass1(const int* __restrict__ node_idx, const int* __restrict__ edge_idx,
    const float* __restrict__ s_node, const float* __restrict__ s_edge,
    float* __restrict__ a_buf, float* amax, int* DnCnt, int* BnCnt) {
  int i = blockIdx.x * 256 + threadIdx.x;
  if (i >= NNZC) return;
  int n = node_idx[i], m = edge_idx[i];
  float a = s_node[n] + s_edge[m];
  a = (a >= 0.f) ? a : 0.2f * a;
  a_buf[i] = a;
  atomicMaxF(&amax[n], a);
  atomicAdd(&DnCnt[n], 1);
  atomicAdd(&BnCnt[m], 1);
}

// ---------------- dual exclusive scan ----------------
__global__ __launch_bounds__(1024) void exscan2_kernel(const int* __restrict__ inA,
    int* __restrict__ outA, int nA, const int* __restrict__ inB, int* __restrict__ outB, int nB) {
  const int* in; int* out; int n;
  if (blockIdx.x == 0) { in = inA; out = outA; n = nA; }
  else                 { in = inB; out = outB; n = nB; }
  __shared__ int sums[1024];
  const int t = threadIdx.x;
  const int chunk = (n + 1023) >> 10;
  const int start = t * chunk;
  const int stop  = min(start + chunk, n);
  int local = 0;
  for (int i = start; i < stop; ++i) local += in[i];
  sums[t] = local;
  __syncthreads();
  for (int o = 1; o < 1024; o <<= 1) {
    int v = (t >= o) ? sums[t - o] : 0;
    __syncthreads();
    sums[t] += v;
    __syncthreads();
  }
  int run = (t == 0) ? 0 : sums[t - 1];
  for (int i = start; i < stop; ++i) { out[i] = run; run += in[i]; }
  if (t == 1023) out[n] = sums[1023];
}

// ---------------- incidence pass 2 ----------------
__global__ void incidence_pass2(const int* __restrict__ node_idx, const int* __restrict__ edge_idx,
    float* __restrict__ a_buf, const float* __restrict__ amax, float* den,
    const int* __restrict__ node_off, const int* __restrict__ edge_off,
    int* node_cur, int* edge_cur, int* node_list, int* edge_list) {
  int i = blockIdx.x * 256 + threadIdx.x;
  if (i >= NNZC) return;
  int n = node_idx[i], m = edge_idx[i];
  float e = __expf(a_buf[i] - amax[n]);
  a_buf[i] = e;
  atomicAdd(&den[n], e);
  int pn = atomicAdd(&node_cur[n], 1);
  node_list[node_off[n] + pn] = i;
  int pm = atomicAdd(&edge_cur[m], 1);
  edge_list[edge_off[m] + pm] = i;
}

// ---------------- edge gather (bf16 xl in, bf16 ef out), 4-way unrolled ----------------
__global__ __launch_bounds__(256) void gather_edge(const int* __restrict__ edge_off,
    const int* __restrict__ edge_list, const int* __restrict__ node_idx,
    const float* __restrict__ a_buf, const float* __restrict__ den,
    const unsigned short* __restrict__ xlb, unsigned short* __restrict__ efb) {
  int m = blockIdx.x;
  int t = threadIdx.x;
  int beg = edge_off[m], end = edge_off[m+1];
  int cnt = end - beg;
  float Binv = (cnt > 0) ? (1.0f / (float)cnt) : 0.f;
  __shared__ int   ln_[128];
  __shared__ float lw_[128];
  float acc0 = 0.f, acc1 = 0.f;
  for (int c = beg; c < end; c += 128) {
    int nchunk = min(128, end - c);
    if (t < nchunk) {
      int i = edge_list[c + t];
      int n = node_idx[i];
      ln_[t] = n;
      lw_[t] = a_buf[i] / (den[n] + 1e-16f) * Binv;
    }
    __syncthreads();
    float a0 = 0.f, a1 = 0.f, a2 = 0.f, a3 = 0.f;
    float b0 = 0.f, b1 = 0.f, b2 = 0.f, b3 = 0.f;
    int j = 0;
    for (; j + 3 < nchunk; j += 4) {
      float w0 = lw_[j], w1 = lw_[j+1], w2 = lw_[j+2], w3 = lw_[j+3];
      const unsigned short* r0 = &xlb[(size_t)ln_[j]   * DD];
      const unsigned short* r1 = &xlb[(size_t)ln_[j+1] * DD];
      const unsigned short* r2 = &xlb[(size_t)ln_[j+2] * DD];
      const unsigned short* r3 = &xlb[(size_t)ln_[j+3] * DD];
      a0 += w0 * bf2f(r0[t]);  b0 += w0 * bf2f(r0[t + 256]);
      a1 += w1 * bf2f(r1[t]);  b1 += w1 * bf2f(r1[t + 256]);
      a2 += w2 * bf2f(r2[t]);  b2 += w2 * bf2f(r2[t + 256]);
      a3 += w3 * bf2f(r3[t]);  b3 += w3 * bf2f(r3[t + 256]);
    }
    for (; j < nchunk; ++j) {
      float w0 = lw_[j];
      const unsigned short* r0 = &xlb[(size_t)ln_[j] * DD];
      a0 += w0 * bf2f(r0[t]);  b0 += w0 * bf2f(r0[t + 256]);
    }
    acc0 += (a0 + a1) + (a2 + a3);
    acc1 += (b0 + b1) + (b2 + b3);
    __syncthreads();
  }
  efb[(size_t)m * DD + t]       = f2bf(acc0);
  efb[(size_t)m * DD + t + 256] = f2bf(acc1);
}

// ---------------- node gather + fused LN1: x1b = LN(x + conv), 4-way unrolled ----------
__global__ __launch_bounds__(256) void gather_node_ln(const int* __restrict__ node_off,
    const int* __restrict__ node_list, const int* __restrict__ edge_idx,
    const float* __restrict__ a_buf, const float* __restrict__ den,
    const unsigned short* __restrict__ efb, const float* __restrict__ bias_h,
    const float* __restrict__ x, const float* __restrict__ g, const float* __restrict__ be,
    unsigned short* __restrict__ x1b) {
  int n = blockIdx.x;
  int t = threadIdx.x;
  int beg = node_off[n], end = node_off[n+1];
  int cnt = end - beg;
  float Dinv = (cnt > 0) ? (1.0f / (float)cnt) : 0.f;
  float wscale = Dinv / (den[n] + 1e-16f);
  __shared__ int   le_[128];
  __shared__ float lw_[128];
  float acc0 = 0.f, acc1 = 0.f;
  for (int c = beg; c < end; c += 128) {
    int nchunk = min(128, end - c);
    if (t < nchunk) {
      int i = node_list[c + t];
      le_[t] = edge_idx[i];
      lw_[t] = a_buf[i] * wscale;
    }
    __syncthreads();
    float a0 = 0.f, a1 = 0.f, a2 = 0.f, a3 = 0.f;
    float b0 = 0.f, b1 = 0.f, b2 = 0.f, b3 = 0.f;
    int j = 0;
    for (; j + 3 < nchunk; j += 4) {
      float w0 = lw_[j], w1 = lw_[j+1], w2 = lw_[j+2], w3 = lw_[j+3];
      const unsigned short* r0 = &efb[(size_t)le_[j]   * DD];
      const unsigned short* r1 = &efb[(size_t)le_[j+1] * DD];
      const unsigned short* r2 = &efb[(size_t)le_[j+2] * DD];
      const unsigned short* r3 = &efb[(size_t)le_[j+3] * DD];
      a0 += w0 * bf2f(r0[t]);  b0 += w0 * bf2f(r0[t + 256]);
      a1 += w1 * bf2f(r1[t]);  b1 += w1 * bf2f(r1[t + 256]);
      a2 += w2 * bf2f(r2[t]);  b2 += w2 * bf2f(r2[t + 256]);
      a3 += w3 * bf2f(r3[t]);  b3 += w3 * bf2f(r3[t + 256]);
    }
    for (; j < nchunk; ++j) {
      float w0 = lw_[j];
      const unsigned short* r0 = &efb[(size_t)le_[j] * DD];
      a0 += w0 * bf2f(r0[t]);  b0 += w0 * bf2f(r0[t + 256]);
    }
    acc0 += (a0 + a1) + (a2 + a3);
    acc1 += (b0 + b1) + (b2 + b3);
    __syncthreads();
  }
  float v0 = x[(size_t)n*DD + t]       + acc0 + bias_h[t];
  float v1 = x[(size_t)n*DD + t + 256] + acc1 + bias_h[t + 256];
  __shared__ float red[4];
  __shared__ float mu_s, rstd_s;
  float s = v0 + v1;
  #pragma unroll
  for (int off = 1; off < 64; off <<= 1) s += __shfl_xor(s, off, 64);
  int wid = t >> 6;
  if ((t & 63) == 0) red[wid] = s;
  __syncthreads();
  if (t == 0) mu_s = (red[0] + red[1] + red[2] + red[3]) / 512.f;
  __syncthreads();
  float mu = mu_s;
  float d0 = v0 - mu, d1 = v1 - mu;
  float vs = d0*d0 + d1*d1;
  #pragma unroll
  for (int off = 1; off < 64; off <<= 1) vs += __shfl_xor(vs, off, 64);
  if ((t & 63) == 0) red[wid] = vs;
  __syncthreads();
  if (t == 0) rstd_s = rsqrtf((red[0] + red[1] + red[2] + red[3]) / 512.f + 1e-5f);
  __syncthreads();
  float rs = rstd_s;
  x1b[(size_t)n*DD + t]       = f2bf(d0 * rs * g[t]       + be[t]);
  x1b[(size_t)n*DD + t + 256] = f2bf(d1 * rs * g[t + 256] + be[t + 256]);
}

// ---------------- LN(a_bf16 + b_bf16) -> bf16 ----------------
__global__ __launch_bounds__(256) void ln_res_bb(const unsigned short* __restrict__ a,
    const unsigned short* __restrict__ b, const float* __restrict__ g,
    const float* __restrict__ be, unsigned short* __restrict__ outb) {
  int r = blockIdx.x;
  int t = threadIdx.x;
  float v0 = bf2f(a[(size_t)r*DD + t])       + bf2f(b[(size_t)r*DD + t]);
  float v1 = bf2f(a[(size_t)r*DD + t + 256]) + bf2f(b[(size_t)r*DD + t + 256]);
  __shared__ float red[4];
  __shared__ float mu_s, rstd_s;
  float s = v0 + v1;
  #pragma unroll
  for (int off = 1; off < 64; off <<= 1) s += __shfl_xor(s, off, 64);
  int wid = t >> 6;
  if ((t & 63) == 0) red[wid] = s;
  __syncthreads();
  if (t == 0) mu_s = (red[0] + red[1] + red[2] + red[3]) / 512.f;
  __syncthreads();
  float mu = mu_s;
  float d0 = v0 - mu, d1 = v1 - mu;
  float vs = d0*d0 + d1*d1;
  #pragma unroll
  for (int off = 1; off < 64; off <<= 1) vs += __shfl_xor(vs, off, 64);
  if ((t & 63) == 0) red[wid] = vs;
  __syncthreads();
  if (t == 0) rstd_s = rsqrtf((red[0] + red[1] + red[2] + red[3]) / 512.f + 1e-5f);
  __syncthreads();
  float rs = rstd_s;
  outb[(size_t)r*DD + t]       = f2bf(d0 * rs * g[t]       + be[t]);
  outb[(size_t)r*DD + t + 256] = f2bf(d1 * rs * g[t + 256] + be[t + 256]);
}

// ---------------- fused final 2 LayerNorms: x3=LN(x2b+ffob); out=LN(x1b+x3) ----------------
__global__ __launch_bounds__(256) void ln_final2(const unsigned short* __restrict__ x2b,
    const unsigned short* __restrict__ ffob, const unsigned short* __restrict__ x1b,
    const float* __restrict__ g1, const float* __restrict__ b1,
    const float* __restrict__ g2, const float* __restrict__ b2,
    float* __restrict__ out) {
  int r = blockIdx.x;
  int t = threadIdx.x;
  __shared__ float red[4];
  __shared__ float sh0, sh1;
  int wid = t >> 6;
  float v0 = bf2f(x2b[(size_t)r*DD + t])       + bf2f(ffob[(size_t)r*DD + t]);
  float v1 = bf2f(x2b[(size_t)r*DD + t + 256]) + bf2f(ffob[(size_t)r*DD + t + 256]);
  float s = v0 + v1;
  #pragma unroll
  for (int off = 1; off < 64; off <<= 1) s += __shfl_xor(s, off, 64);
  if ((t & 63) == 0) red[wid] = s;
  __syncthreads();
  if (t == 0) sh0 = (red[0] + red[1] + red[2] + red[3]) / 512.f;
  __syncthreads();
  float mu = sh0;
  float d0 = v0 - mu, d1 = v1 - mu;
  float vs = d0*d0 + d1*d1;
  #pragma unroll
  for (int off = 1; off < 64; off <<= 1) vs += __shfl_xor(vs, off, 64);
  if ((t & 63) == 0) red[wid] = vs;
  __syncthreads();
  if (t == 0) sh1 = rsqrtf((red[0] + red[1] + red[2] + red[3]) / 512.f + 1e-5f);
  __syncthreads();
  float rs = sh1;
  float x30 = d0 * rs * g1[t]       + b1[t];
  float x31 = d1 * rs * g1[t + 256] + b1[t + 256];
  __syncthreads();
  float u0 = bf2f(x1b[(size_t)r*DD + t])       + x30;
  float u1 = bf2f(x1b[(size_t)r*DD + t + 256]) + x31;
  s = u0 + u1;
  #pragma unroll
  for (int off = 1; off < 64; off <<= 1) s += __shfl_xor(s, off, 64);
  if ((t & 63) == 0) red[wid] = s;
  __syncthreads();
  if (t == 0) sh0 = (red[0] + red[1] + red[2] + red[3]) / 512.f;
  __syncthreads();
  mu = sh0;
  d0 = u0 - mu; d1 = u1 - mu;
  vs = d0*d0 + d1*d1;
  #pragma unroll
  for (int off = 1; off < 64; off <<= 1) vs += __shfl_xor(vs, off, 64);
  if ((t & 63) == 0) red[wid] = vs;
  __syncthreads();
  if (t == 0) sh1 = rsqrtf((red[0] + red[1] + red[2] + red[3]) / 512.f + 1e-5f);
  __syncthreads();
  rs = sh1;
  out[(size_t)r*DD + t]       = d0 * rs * g2[t]       + b2[t];
  out[(size_t)r*DD + t + 256] = d1 * rs * g2[t + 256] + b2[t + 256];
}

// ---------------- MFMA flash attention partial (split-K), KVBLK=64, swapped-QK^T ----
// Reg-staged DOUBLE LDS buffer: one barrier per tile (write idle buffer during compute).
__global__ __launch_bounds__(256) void attn_mfma_part(const unsigned short* __restrict__ qkvbb,
                                                      const unsigned short* __restrict__ Vtb,
                                                      unsigned short* __restrict__ Opartb,
                                                      float* __restrict__ ml) {
  const int head = blockIdx.y;
  const int z = blockIdx.z;
  const int q0 = blockIdx.x * 64;
  const int t = threadIdx.x;
  const int w = t >> 6;
  const int l = t & 63;
  const int lg = l >> 4;
  const int lid = l & 15;
  const float sc = 0.125f * 1.44269504f;    // 1/sqrt(64) * log2(e)
  const float THRraw = 44.36f;              // 8 / sc

  __shared__ __align__(16) unsigned short Kl[2][64*64];
  __shared__ __align__(16) unsigned short Vl[2][64*64];

  bf16x8 qa[2];
  {
    const int qrow = q0 + w*16 + lid;
    const unsigned short* qp = &qkvbb[(size_t)qrow*1536 + head*64];
    qa[0] = *(const bf16x8*)&qp[lg*8];
    qa[1] = *(const bf16x8*)&qp[32 + lg*8];
  }

  float m = -1e30f, msc = -1e30f, lsum = 0.f;
  f32x4 o[4];
  #pragma unroll
  for (int dt = 0; dt < 4; ++dt) o[dt] = (f32x4)0.f;

  const unsigned short* Kh = qkvbb + 512 + head*64;          // row stride 1536
  const unsigned short* Vh = Vtb + (size_t)head*64*NN;
  const int kt0 = z * (NN / NSPLIT);
  const int kt1 = kt0 + (NN / NSPLIT);

  const int srow0 = t >> 3,        scc = (t & 7) * 8;
  const int srow1 = 32 + (t >> 3);
  const int sdst0 = (srow0*64 + scc) ^ ((srow0 & 7) << 3);
  const int sdst1 = (srow1*64 + scc) ^ ((srow1 & 7) << 3);
  const int kperm0 = 8*((srow0>>2)&3) + 4*((srow0>>4)&1) + (srow0&3) + 32*(srow0>>5);
  const int kperm1 = 8*((srow1>>2)&3) + 4*((srow1>>4)&1) + (srow1&3) + 32*(srow1>>5);
  ulonglong2 kreg0, kreg1, vreg0, vreg1;

#define LOADKV(ktv) do { \
    kreg0 = *(const ulonglong2*)&Kh[(size_t)((ktv) + kperm0)*1536 + scc]; \
    vreg0 = *(const ulonglong2*)&Vh[(size_t)srow0*NN + (ktv) + scc]; \
    kreg1 = *(const ulonglong2*)&Kh[(size_t)((ktv) + kperm1)*1536 + scc]; \
    vreg1 = *(const ulonglong2*)&Vh[(size_t)srow1*NN + (ktv) + scc]; \
  } while (0)
#define STORKV(b) do { \
    *(ulonglong2*)&Kl[b][sdst0] = kreg0; *(ulonglong2*)&Vl[b][sdst0] = vreg0; \
    *(ulonglong2*)&Kl[b][sdst1] = kreg1; *(ulonglong2*)&Vl[b][sdst1] = vreg1; \
  } while (0)

  LOADKV(kt0);
  STORKV(0);
  __syncthreads();

  int cur = 0;
  for (int kt = kt0; kt < kt1; kt += 64) {
    const bool hn = (kt + 64) < kt1;
    if (hn) LOADKV(kt + 64);   // issue early; lands during compute (T14)
    const unsigned short* Klc = &Kl[cur][0];
    const unsigned short* Vlc = &Vl[cur][0];

    // ---- S^T = K Q^T (swapped operands) ----
    f32x4 s[4];
    #pragma unroll
    for (int n = 0; n < 4; ++n) s[n] = (f32x4)0.f;
    __builtin_amdgcn_s_setprio(1);
    #pragma unroll
    for (int n = 0; n < 4; ++n) {
      int tok = n*16 + lid;
      #pragma unroll
      for (int hf = 0; hf < 2; ++hf) {
        int didx = (tok*64 + hf*32 + lg*8) ^ ((tok & 7) << 3);
        bf16x8 kb = *(const bf16x8*)&Klc[didx];
        s[n] = __builtin_amdgcn_mfma_f32_16x16x32_bf16(kb, qa[hf], s[n], 0, 0, 0);
      }
    }
    __builtin_amdgcn_s_setprio(0);

    // ---- in-register online softmax, raw units (q = lid per lane) ----
    float a0 = fmaxf(fmaxf(s[0][0], s[0][1]), s[0][2]);
    float a1 = fmaxf(fmaxf(s[0][3], s[1][0]), s[1][1]);
    float a2 = fmaxf(fmaxf(s[1][2], s[1][3]), s[2][0]);
    float a3 = fmaxf(fmaxf(s[2][1], s[2][2]), s[2][3]);
    float a4 = fmaxf(fmaxf(s[3][0], s[3][1]), s[3][2]);
    float mx = fmaxf(fmaxf(fmaxf(a0, a1), a2), fmaxf(fmaxf(a3, a4), s[3][3]));
    mx = fmaxf(mx, __shfl_xor(mx, 16, 64));
    mx = fmaxf(mx, __shfl_xor(mx, 32, 64));
    if (!__all(mx <= m + THRraw)) {
      float mn = fmaxf(m, mx);
      float c = exp2f((m - mn) * sc);
      m = mn;
      msc = m * sc;
      lsum *= c;
      #pragma unroll
      for (int r = 0; r < 4; ++r) {
        float cr = __shfl(c, lg*4 + r, 64);
        #pragma unroll
        for (int dt = 0; dt < 4; ++dt) o[dt][r] *= cr;
      }
    }
    float ps = 0.f;
    #pragma unroll
    for (int n = 0; n < 4; ++n)
      #pragma unroll
      for (int r = 0; r < 4; ++r) {
        float p = exp2f(fmaf(s[n][r], sc, -msc));
        s[n][r] = p;
        ps += p;
      }
    ps += __shfl_xor(ps, 16, 64);
    ps += __shfl_xor(ps, 32, 64);
    lsum += ps;

    // ---- P repack: fully in-lane ----
    union { bf16x8 v; unsigned int u[4]; } pa[2];
    #pragma unroll
    for (int hf = 0; hf < 2; ++hf) {
      asm("v_cvt_pk_bf16_f32 %0, %1, %2" : "=v"(pa[hf].u[0]) : "v"(s[2*hf][0]),   "v"(s[2*hf][1]));
      asm("v_cvt_pk_bf16_f32 %0, %1, %2" : "=v"(pa[hf].u[1]) : "v"(s[2*hf][2]),   "v"(s[2*hf][3]));
      asm("v_cvt_pk_bf16_f32 %0, %1, %2" : "=v"(pa[hf].u[2]) : "v"(s[2*hf+1][0]), "v"(s[2*hf+1][1]));
      asm("v_cvt_pk_bf16_f32 %0, %1, %2" : "=v"(pa[hf].u[3]) : "v"(s[2*hf+1][2]), "v"(s[2*hf+1][3]));
    }

    // ---- O += P V ----
    __builtin_amdgcn_s_setprio(1);
    #pragma unroll
    for (int dt = 0; dt < 4; ++dt) {
      int drow = dt*16 + lid;
      #pragma unroll
      for (int hf = 0; hf < 2; ++hf) {
        int didx = (drow*64 + hf*32 + lg*8) ^ ((drow & 7) << 3);
        bf16x8 vb = *(const bf16x8*)&Vlc[didx];
        o[dt] = __builtin_amdgcn_mfma_f32_16x16x32_bf16(pa[hf].v, vb, o[dt], 0, 0, 0);
      }
    }
    __builtin_amdgcn_s_setprio(0);

    // write prefetched tile to the idle buffer (nobody reads it: barrier of the
    // previous iteration guaranteed all waves finished reading cur^1).
    if (hn) STORKV(cur ^ 1);
    __syncthreads();           // single barrier per tile
    cur ^= 1;
  }
#undef LOADKV
#undef STORKV

  // ---- epilogue: bf16 partial O (rows q=lg*4+r) + per-lane (msc, l) for q=lid ----
  #pragma unroll
  for (int r = 0; r < 4; ++r) {
    int q = q0 + w*16 + lg*4 + r;
    size_t base = ((size_t)(z*HH + head)*NN + q)*64;
    #pragma unroll
    for (int dt = 0; dt < 4; ++dt)
      Opartb[base + dt*16 + lid] = f2bf(o[dt][r]);
  }
  if (l < 16) {
    int q = q0 + w*16 + l;
    size_t mb = ((size_t)(z*HH + head)*NN + q)*2;
    ml[mb]     = msc;
    ml[mb + 1] = lsum;
  }
}

// ---------------- combine split-K partials -> ctx bf16 ----------------
__global__ __launch_bounds__(256) void attn_combine(const unsigned short* __restrict__ Opartb,
                                                    const float* __restrict__ ml,
                                                    unsigned short* __restrict__ ctxb) {
  const int w = threadIdx.x >> 6, lane = threadIdx.x & 63;
  const int row = blockIdx.x * 4 + w;     // 0 .. NN*HH-1
  const int q = row >> 3, head = row & 7;
  float ms[NSPLIT], ls[NSPLIT];
  float mglob = -1e30f;
  #pragma unroll
  for (int s = 0; s < NSPLIT; ++s) {
    size_t mb = ((size_t)(s*HH + head)*NN + q)*2;
    ms[s] = ml[mb]; ls[s] = ml[mb + 1];
    mglob = fmaxf(mglob, ms[s]);
  }
  float lt = 0.f, ov = 0.f;
  #pragma unroll
  for (int s = 0; s < NSPLIT; ++s) {
    float wgt = exp2f(ms[s] - mglob);
    lt += ls[s] * wgt;
    ov += bf2f(Opartb[((size_t)(s*HH + head)*NN + q)*64 + lane]) * wgt;
  }
  ctxb[(size_t)q*DD + head*64 + lane] = f2bf(ov / lt);
}

// ---------------- host ----------------
extern "C" void kernel_launch(void* const* d_in, const int* in_sizes, int n_in,
                              void* d_out, int out_size, void* d_ws, size_t ws_size,
                              hipStream_t stream) {
  const float* x       = (const float*)d_in[0];
  const int*   hidx    = (const int*)d_in[1];
  const float* hattr   = (const float*)d_in[2];
  const float* Wh      = (const float*)d_in[3];
  const float* att     = (const float*)d_in[4];
  const float* bias_h  = (const float*)d_in[5];
  const float* ln1_g   = (const float*)d_in[6];
  const float* ln1_b   = (const float*)d_in[7];
  const float* ln2_g   = (const float*)d_in[8];
  const float* ln2_b   = (const float*)d_in[9];
  const float* in_proj_w  = (const float*)d_in[10];
  const float* in_proj_b  = (const float*)d_in[11];
  const float* out_proj_w = (const float*)d_in[12];
  const float* out_proj_b = (const float*)d_in[13];
  const float* ff1_w   = (const float*)d_in[14];
  const float* ff1_b   = (const float*)d_in[15];
  const float* ff2_w   = (const float*)d_in[16];
  const float* ff2_b   = (const float*)d_in[17];
  const float* tln1_g  = (const float*)d_in[18];
  const float* tln1_b  = (const float*)d_in[19];
  const float* tln2_g  = (const float*)d_in[20];
  const float* tln2_b  = (const float*)d_in[21];
  const int* node_idx = hidx;
  const int* edge_idx = hidx + NNZC;

  char* ws = (char*)d_ws;
  size_t off = 0;
  auto alloc = [&](size_t bytes) -> void* {
    void* p = ws + off;
    off = (off + bytes + 63) & ~(size_t)63;
    return p;
  };
  float* s_node   = (float*)alloc(sizeof(float)*NN);
  float* s_edge   = (float*)alloc(sizeof(float)*MM);
  float* a_buf    = (float*)alloc(sizeof(float)*NNZC);
  float* amax     = (float*)alloc(sizeof(float)*NN);
  float* den      = (float*)alloc(sizeof(float)*NN);
  int*   DnCnt    = (int*)alloc(sizeof(int)*NN);
  int*   BnCnt    = (int*)alloc(sizeof(int)*MM);
  int*   node_off = (int*)alloc(sizeof(int)*(NN+1));
  int*   edge_off = (int*)alloc(sizeof(int)*(MM+1));
  int*   node_cur = (int*)alloc(sizeof(int)*NN);
  int*   edge_cur = (int*)alloc(sizeof(int)*MM);
  int*   node_list= (int*)alloc(sizeof(int)*NNZC);
  int*   edge_list= (int*)alloc(sizeof(int)*NNZC);
  unsigned short* xhb   = (unsigned short*)alloc(sizeof(unsigned short)*(NN+MM)*DD);  // [x; hattr]
  unsigned short* xelb  = (unsigned short*)alloc(sizeof(unsigned short)*(NN+MM)*DD);  // [xl; el]
  unsigned short* efb   = (unsigned short*)alloc(sizeof(unsigned short)*MM*DD);
  unsigned short* qkvbb = (unsigned short*)alloc(sizeof(unsigned short)*NN*3*DD);
  unsigned short* Vtb   = (unsigned short*)alloc(sizeof(unsigned short)*NN*DD);
  unsigned short* Whb   = (unsigned short*)alloc(sizeof(unsigned short)*DD*DD);
  unsigned short* ipwb  = (unsigned short*)alloc(sizeof(unsigned short)*3*DD*DD);
  unsigned short* opwb  = (unsigned short*)alloc(sizeof(unsigned short)*DD*DD);
  unsigned short* ff1wb = (unsigned short*)alloc(sizeof(unsigned short)*DFFC*DD);
  unsigned short* ff2wb = (unsigned short*)alloc(sizeof(unsigned short)*DD*DFFC);
  unsigned short* x1b   = (unsigned short*)alloc(sizeof(unsigned short)*NN*DD);
  unsigned short* x2b   = (unsigned short*)alloc(sizeof(unsigned short)*NN*DD);
  unsigned short* ctxb  = (unsigned short*)alloc(sizeof(unsigned short)*NN*DD);
  unsigned short* attn_outb = (unsigned short*)alloc(sizeof(unsigned short)*NN*DD);
  // "late" region: attention partials alias FFN-phase buffers (dead before ff1).
  char* late = (char*)alloc(20u*1024*1024);
  unsigned short* Opartb = (unsigned short*)late;                        // 16 MB (attn phase)
  float*          mlb    = (float*)(late + 16u*1024*1024);               // 1 MB (attn phase)
  unsigned short* ffhb   = (unsigned short*)late;                        // 16 MB (FFN phase)
  unsigned short* ffob   = (unsigned short*)(late + 16u*1024*1024);      // 4 MB (FFN phase)
  unsigned short* xlb = xelb;
  unsigned short* elb = xelb + (size_t)NN*DD;
  (void)ws_size; (void)in_sizes; (void)n_in; (void)out_size;

  dim3 b256(256);
  // one-time bf16 conversions (single batched launch); x and hattr land adjacent in xhb
  f2b_multi<<<dim3(256, 7), b256, 0, stream>>>(
      x, xhb, NN*DD/8,  hattr, xhb + (size_t)NN*DD, MM*DD/8,  Wh, Whb, DD*DD/8,
      in_proj_w, ipwb, 3*DD*DD/8,  out_proj_w, opwb, DD*DD/8,
      ff1_w, ff1wb, DFFC*DD/8,  ff2_w, ff2wb, DD*DFFC/8);

  // [xl; el] = [x; hattr] @ Wh^T  (merged, BN=64)
  gemm_bt_bf16_n64<<<dim3((NN+MM)/128, DD/64), b256, 0, stream>>>(xhb, Whb, nullptr, xelb, DD, DD, nullptr);
  // sparse hypergraph conv
  rowdot_both<<<(NN+MM)/4, b256, 0, stream>>>(xlb, elb, att, s_node, s_edge);
  init_kernel<<<NN/256, b256, 0, stream>>>(amax, den, DnCnt, BnCnt, node_cur, edge_cur);
  incidence_pass1<<<NNZC/256, b256, 0, stream>>>(node_idx, edge_idx, s_node, s_edge,
                                                 a_buf, amax, DnCnt, BnCnt);
  exscan2_kernel<<<2, 1024, 0, stream>>>(DnCnt, node_off, NN, BnCnt, edge_off, MM);
  incidence_pass2<<<NNZC/256, b256, 0, stream>>>(node_idx, edge_idx, a_buf, amax, den,
                                                 node_off, edge_off, node_cur, edge_cur,
                                                 node_list, edge_list);
  gather_edge<<<MM, b256, 0, stream>>>(edge_off, edge_list, node_idx, a_buf, den, xlb, efb);
  // gather_node + fused LN1 -> x1b (bf16 residual stream)
  gather_node_ln<<<NN, b256, 0, stream>>>(node_off, node_list, edge_idx, a_buf, den, efb,
                                          bias_h, x, ln1_g, ln1_b, x1b);
  // qkv (BN=64; V-plane blocks write transposed Vtb directly)
  gemm_bt_bf16_n64<<<dim3(NN/128, (3*DD)/64), b256, 0, stream>>>(x1b, ipwb, in_proj_b, qkvbb, 3*DD, DD, Vtb);
  // attention (bf16 MFMA, split-K x4, KVBLK=64 + combine)
  attn_mfma_part<<<dim3(NN/64, HH, NSPLIT), b256, 0, stream>>>(qkvbb, Vtb, Opartb, mlb);
  attn_combine<<<NN*HH/4, b256, 0, stream>>>(Opartb, mlb, ctxb);
  // out_proj (BN=64)
  gemm_bt_bf16_n64<<<dim3(NN/128, DD/64), b256, 0, stream>>>(ctxb, opwb, out_proj_b, attn_outb, DD, DD, nullptr);
  // x2b = LN(x1b + attn_outb)
  ln_res_bb<<<NN, b256, 0, stream>>>(x1b, attn_outb, tln1_g, tln1_b, x2b);
  // ffn: ff1 (128x128 tile; relu, bf16 out), ff2 (BN=64, K=2048)
  gemm_bt_bf16<<<dim3(NN/128, DFFC/128), b256, 0, stream>>>(x2b, ff1wb, ff1_b, nullptr, ffhb, DFFC, DD, 1);
  gemm_bt_bf16_n64<<<dim3(NN/128, DD/64), b256, 0, stream>>>(ffhb, ff2wb, ff2_b, ffob, DD, DFFC, nullptr);
  // x3 = LN(x2b + ffob); out = LN(x1b + x3)  (fused)
  ln_final2<<<NN, b256, 0, stream>>>(x2b, ffob, x1b, tln2_g, tln2_b, ln2_g, ln2_b, (float*)d_out);
}

// Round 17
// 258.091 us; speedup vs baseline: 1.0531x; 1.0086x over previous
//
#include <hip/hip_runtime.h>
#include <math.h>

#define NN   4096
#define MM   1024
#define NNZC 65536
#define DD   512
#define HH   8
#define DHH  64
#define DFFC 2048
#define NSPLIT 4

typedef short bf16x8 __attribute__((ext_vector_type(8)));
typedef float f32x4  __attribute__((ext_vector_type(4)));

static __device__ inline unsigned short f2bf(float f) {
  union { float f; unsigned int u; } v; v.f = f;
  unsigned int r = v.u + 0x7fff + ((v.u >> 16) & 1);   // RNE
  return (unsigned short)(r >> 16);
}
static __device__ inline float bf2f(unsigned short u) {
  return __uint_as_float((unsigned int)u << 16);
}

__device__ inline void gload16(const void* g, void* l) {
  __builtin_amdgcn_global_load_lds(
      (const __attribute__((address_space(1))) void*)g,
      (__attribute__((address_space(3))) void*)l, 16, 0, 0);
}

// ---------------- utility ----------------
__device__ inline void atomicMaxF(float* addr, float val) {
  if (val >= 0.f) atomicMax((int*)addr, __float_as_int(val));
  else            atomicMin((unsigned int*)addr, __float_as_uint(val));
}

// ---------------- init ----------------
__global__ void init_kernel(float* amax, float* den, int* DnCnt, int* BnCnt,
                            int* node_cur, int* edge_cur) {
  int i = blockIdx.x * 256 + threadIdx.x;
  if (i < NN) { amax[i] = -INFINITY; den[i] = 0.f; DnCnt[i] = 0; node_cur[i] = 0; }
  if (i < MM) { BnCnt[i] = 0; edge_cur[i] = 0; }
}

// ---------------- batched fp32 -> bf16 convert (7 segments, 1 launch) ----------------
__global__ __launch_bounds__(256) void f2b_multi(
    const float* s0, unsigned short* d0, int n0,
    const float* s1, unsigned short* d1, int n1,
    const float* s2, unsigned short* d2, int n2,
    const float* s3, unsigned short* d3, int n3,
    const float* s4, unsigned short* d4, int n4,
    const float* s5, unsigned short* d5, int n5,
    const float* s6, unsigned short* d6, int n6) {
  const float* in; unsigned short* out; int n8;
  switch (blockIdx.y) {
    case 0: in=s0; out=d0; n8=n0; break;
    case 1: in=s1; out=d1; n8=n1; break;
    case 2: in=s2; out=d2; n8=n2; break;
    case 3: in=s3; out=d3; n8=n3; break;
    case 4: in=s4; out=d4; n8=n4; break;
    case 5: in=s5; out=d5; n8=n5; break;
    default: in=s6; out=d6; n8=n6; break;
  }
  for (int i = blockIdx.x*256 + threadIdx.x; i < n8; i += gridDim.x*256) {
    float4 v0 = *(const float4*)&in[(size_t)i*8];
    float4 v1 = *(const float4*)&in[(size_t)i*8 + 4];
    unsigned short w[8];
    w[0]=f2bf(v0.x); w[1]=f2bf(v0.y); w[2]=f2bf(v0.z); w[3]=f2bf(v0.w);
    w[4]=f2bf(v1.x); w[5]=f2bf(v1.y); w[6]=f2bf(v1.z); w[7]=f2bf(v1.w);
    *(ulonglong2*)&out[(size_t)i*8] = *(ulonglong2*)w;
  }
}

// ---------------- bf16 MFMA NT GEMM, 128x128 tile (ff1) ----------------
__global__ __launch_bounds__(256) void gemm_bt_bf16(
    const unsigned short* __restrict__ A, const unsigned short* __restrict__ B,
    const float* __restrict__ bias, float* __restrict__ Cf,
    unsigned short* __restrict__ Cb, int N, int K, int relu) {
  __shared__ __align__(16) unsigned short Al[128*64];
  __shared__ __align__(16) unsigned short Bl[128*64];
  const int t = threadIdx.x;
  const int w = t >> 6, l = t & 63;
  const int lg = l >> 4, lid = l & 15;
  const int wr = w >> 1, wc = w & 1;
  const int bm = blockIdx.x * 128, bn = blockIdx.y * 128;

  f32x4 acc[4][4];
  #pragma unroll
  for (int mi = 0; mi < 4; ++mi)
    #pragma unroll
    for (int ni = 0; ni < 4; ++ni) acc[mi][ni] = (f32x4)0.f;

  for (int k0 = 0; k0 < K; k0 += 64) {
    #pragma unroll
    for (int i = 0; i < 4; ++i) {
      int cid = i*256 + t;
      int row = cid >> 3, cp = cid & 7;
      int gc = cp ^ (row & 7);
      gload16(&A[(size_t)(bm + row)*K + k0 + gc*8], &Al[cid*8]);
      gload16(&B[(size_t)(bn + row)*K + k0 + gc*8], &Bl[cid*8]);
    }
    asm volatile("s_waitcnt vmcnt(0)" ::: "memory");
    __syncthreads();
    #pragma unroll
    for (int ks = 0; ks < 2; ++ks) {
      bf16x8 af[4], bfr[4];
      #pragma unroll
      for (int mi = 0; mi < 4; ++mi) {
        int r = wr*64 + mi*16 + lid;
        af[mi] = *(const bf16x8*)&Al[r*64 + ((ks*4 + lg) ^ (r & 7))*8];
      }
      #pragma unroll
      for (int ni = 0; ni < 4; ++ni) {
        int r = wc*64 + ni*16 + lid;
        bfr[ni] = *(const bf16x8*)&Bl[r*64 + ((ks*4 + lg) ^ (r & 7))*8];
      }
      __builtin_amdgcn_s_setprio(1);
      #pragma unroll
      for (int mi = 0; mi < 4; ++mi)
        #pragma unroll
        for (int ni = 0; ni < 4; ++ni)
          acc[mi][ni] = __builtin_amdgcn_mfma_f32_16x16x32_bf16(af[mi], bfr[ni], acc[mi][ni], 0, 0, 0);
      __builtin_amdgcn_s_setprio(0);
    }
    __syncthreads();
  }

  #pragma unroll
  for (int ni = 0; ni < 4; ++ni) {
    int col = bn + wc*64 + ni*16 + lid;
    float bv = bias ? bias[col] : 0.f;
    #pragma unroll
    for (int mi = 0; mi < 4; ++mi) {
      #pragma unroll
      for (int rg = 0; rg < 4; ++rg) {
        int row = bm + wr*64 + mi*16 + lg*4 + rg;
        float v = acc[mi][ni][rg] + bv;
        if (relu) v = fmaxf(v, 0.f);
        if (Cf) Cf[(size_t)row*N + col] = v;
        if (Cb) Cb[(size_t)row*N + col] = f2bf(v);
      }
    }
  }
}

// ---------------- bf16 MFMA NT GEMM, 128x64 tile (small-N GEMMs) ----------------
__global__ __launch_bounds__(256) void gemm_bt_bf16_n64(
    const unsigned short* __restrict__ A, const unsigned short* __restrict__ B,
    const float* __restrict__ bias, unsigned short* __restrict__ Cb, int N, int K,
    unsigned short* __restrict__ VtbOpt) {
  __shared__ __align__(16) unsigned short Al[128*64];
  __shared__ __align__(16) unsigned short Bl[64*64];
  const int t = threadIdx.x;
  const int w = t >> 6, l = t & 63;
  const int lg = l >> 4, lid = l & 15;
  const int wr = w >> 1, wc = w & 1;
  const int bm = blockIdx.x * 128, bn = blockIdx.y * 64;

  f32x4 acc[4][2];
  #pragma unroll
  for (int mi = 0; mi < 4; ++mi)
    #pragma unroll
    for (int ni = 0; ni < 2; ++ni) acc[mi][ni] = (f32x4)0.f;

  for (int k0 = 0; k0 < K; k0 += 64) {
    #pragma unroll
    for (int i = 0; i < 4; ++i) {
      int cid = i*256 + t;
      int row = cid >> 3, cp = cid & 7;
      int gc = cp ^ (row & 7);
      gload16(&A[(size_t)(bm + row)*K + k0 + gc*8], &Al[cid*8]);
    }
    #pragma unroll
    for (int i = 0; i < 2; ++i) {
      int cid = i*256 + t;
      int row = cid >> 3, cp = cid & 7;
      int gc = cp ^ (row & 7);
      gload16(&B[(size_t)(bn + row)*K + k0 + gc*8], &Bl[cid*8]);
    }
    asm volatile("s_waitcnt vmcnt(0)" ::: "memory");
    __syncthreads();
    #pragma unroll
    for (int ks = 0; ks < 2; ++ks) {
      bf16x8 af[4], bfr[2];
      #pragma unroll
      for (int mi = 0; mi < 4; ++mi) {
        int r = wr*64 + mi*16 + lid;
        af[mi] = *(const bf16x8*)&Al[r*64 + ((ks*4 + lg) ^ (r & 7))*8];
      }
      #pragma unroll
      for (int ni = 0; ni < 2; ++ni) {
        int r = wc*32 + ni*16 + lid;
        bfr[ni] = *(const bf16x8*)&Bl[r*64 + ((ks*4 + lg) ^ (r & 7))*8];
      }
      __builtin_amdgcn_s_setprio(1);
      #pragma unroll
      for (int mi = 0; mi < 4; ++mi)
        #pragma unroll
        for (int ni = 0; ni < 2; ++ni)
          acc[mi][ni] = __builtin_amdgcn_mfma_f32_16x16x32_bf16(af[mi], bfr[ni], acc[mi][ni], 0, 0, 0);
      __builtin_amdgcn_s_setprio(0);
    }
    __syncthreads();
  }

  if (VtbOpt && bn >= 1024) {
    #pragma unroll
    for (int ni = 0; ni < 2; ++ni) {
      int col = bn + wc*32 + ni*16 + lid;
      float bv = bias ? bias[col] : 0.f;
      int d = col - 1024;
      int h = d >> 6, dd = d & 63;
      #pragma unroll
      for (int mi = 0; mi < 4; ++mi) {
        int tok0 = bm + wr*64 + mi*16 + lg*4;
        ushort4 w4;
        w4.x = f2bf(acc[mi][ni][0] + bv);
        w4.y = f2bf(acc[mi][ni][1] + bv);
        w4.z = f2bf(acc[mi][ni][2] + bv);
        w4.w = f2bf(acc[mi][ni][3] + bv);
        *(ushort4*)&VtbOpt[(size_t)h*64*NN + (size_t)dd*NN + tok0] = w4;
      }
    }
  } else {
    #pragma unroll
    for (int ni = 0; ni < 2; ++ni) {
      int col = bn + wc*32 + ni*16 + lid;
      float bv = bias ? bias[col] : 0.f;
      #pragma unroll
      for (int mi = 0; mi < 4; ++mi) {
        #pragma unroll
        for (int rg = 0; rg < 4; ++rg) {
          int row = bm + wr*64 + mi*16 + lg*4 + rg;
          Cb[(size_t)row*N + col] = f2bf(acc[mi][ni][rg] + bv);
        }
      }
    }
  }
}

// ---------------- merged row dots ----------------
__global__ __launch_bounds__(256) void rowdot_both(const unsigned short* __restrict__ xlb,
    const unsigned short* __restrict__ elb, const float* __restrict__ att,
    float* __restrict__ s_node, float* __restrict__ s_edge) {
  int w = (blockIdx.x * 256 + threadIdx.x) >> 6;
  int lane = threadIdx.x & 63;
  const unsigned short* xr;
  const float* vec;
  if (w < NN) { xr = &xlb[(size_t)w * DD]; vec = att; }
  else        { xr = &elb[(size_t)(w - NN) * DD]; vec = att + DD; }
  float s = 0.f;
  #pragma unroll
  for (int j = 0; j < 8; ++j) s += bf2f(xr[lane + 64*j]) * vec[lane + 64*j];
  #pragma unroll
  for (int off = 1; off < 64; off <<= 1) s += __shfl_xor(s, off, 64);
  if (lane == 0) {
    if (w < NN) s_node[w] = s;
    else        s_edge[w - NN] = s;
  }
}

// ---------------- incidence pass 1 ----------------
__global__ void incidence_pass1(const int* __restrict__ node_idx, const int* __restrict__ edge_idx,
    const float* __restrict__ s_node, const float* __restrict__ s_edge,
    float* __restrict__ a_buf, float* amax, int* DnCnt, int* BnCnt) {
  int i = blockIdx.x * 256 + threadIdx.x;
  if (i >= NNZC) return;
  int n = node_idx[i], m = edge_idx[i];
  float a = s_node[n] + s_edge[m];
  a = (a >= 0.f) ? a : 0.2f * a;
  a_buf[i] = a;
  atomicMaxF(&amax[n], a);
  atomicAdd(&DnCnt[n], 1);
  atomicAdd(&BnCnt[m], 1);
}

// ---------------- dual exclusive scan ----------------
__global__ __launch_bounds__(1024) void exscan2_kernel(const int* __restrict__ inA,
    int* __restrict__ outA, int nA, const int* __restrict__ inB, int* __restrict__ outB, int nB) {
  const int* in; int* out; int n;
  if (blockIdx.x == 0) { in = inA; out = outA; n = nA; }
  else                 { in = inB; out = outB; n = nB; }
  __shared__ int sums[1024];
  const int t = threadIdx.x;
  const int chunk = (n + 1023) >> 10;
  const int start = t * chunk;
  const int stop  = min(start + chunk, n);
  int local = 0;
  for (int i = start; i < stop; ++i) local += in[i];
  sums[t] = local;
  __syncthreads();
  for (int o = 1; o < 1024; o <<= 1) {
    int v = (t >= o) ? sums[t - o] : 0;
    __syncthreads();
    sums[t] += v;
    __syncthreads();
  }
  int run = (t == 0) ? 0 : sums[t - 1];
  for (int i = start; i < stop; ++i) { out[i] = run; run += in[i]; }
  if (t == 1023) out[n] = sums[1023];
}

// ---------------- incidence pass 2 ----------------
__global__ void incidence_pass2(const int* __restrict__ node_idx, const int* __restrict__ edge_idx,
    float* __restrict__ a_buf, const float* __restrict__ amax, float* den,
    const int* __restrict__ node_off, const int* __restrict__ edge_off,
    int* node_cur, int* edge_cur, int* node_list, int* edge_list) {
  int i = blockIdx.x * 256 + threadIdx.x;
  if (i >= NNZC) return;
  int n = node_idx[i], m = edge_idx[i];
  float e = __expf(a_buf[i] - amax[n]);
  a_buf[i] = e;
  atomicAdd(&den[n], e);
  int pn = atomicAdd(&node_cur[n], 1);
  node_list[node_off[n] + pn] = i;
  int pm = atomicAdd(&edge_cur[m], 1);
  edge_list[edge_off[m] + pm] = i;
}

// ---------------- edge gather (bf16 xl in, bf16 ef out), 4-way unrolled ----------------
__global__ __launch_bounds__(256) void gather_edge(const int* __restrict__ edge_off,
    const int* __restrict__ edge_list, const int* __restrict__ node_idx,
    const float* __restrict__ a_buf, const float* __restrict__ den,
    const unsigned short* __restrict__ xlb, unsigned short* __restrict__ efb) {
  int m = blockIdx.x;
  int t = threadIdx.x;
  int beg = edge_off[m], end = edge_off[m+1];
  int cnt = end - beg;
  float Binv = (cnt > 0) ? (1.0f / (float)cnt) : 0.f;
  __shared__ int   ln_[128];
  __shared__ float lw_[128];
  float acc0 = 0.f, acc1 = 0.f;
  for (int c = beg; c < end; c += 128) {
    int nchunk = min(128, end - c);
    if (t < nchunk) {
      int i = edge_list[c + t];
      int n = node_idx[i];
      ln_[t] = n;
      lw_[t] = a_buf[i] / (den[n] + 1e-16f) * Binv;
    }
    __syncthreads();
    float a0 = 0.f, a1 = 0.f, a2 = 0.f, a3 = 0.f;
    float b0 = 0.f, b1 = 0.f, b2 = 0.f, b3 = 0.f;
    int j = 0;
    for (; j + 3 < nchunk; j += 4) {
      float w0 = lw_[j], w1 = lw_[j+1], w2 = lw_[j+2], w3 = lw_[j+3];
      const unsigned short* r0 = &xlb[(size_t)ln_[j]   * DD];
      const unsigned short* r1 = &xlb[(size_t)ln_[j+1] * DD];
      const unsigned short* r2 = &xlb[(size_t)ln_[j+2] * DD];
      const unsigned short* r3 = &xlb[(size_t)ln_[j+3] * DD];
      a0 += w0 * bf2f(r0[t]);  b0 += w0 * bf2f(r0[t + 256]);
      a1 += w1 * bf2f(r1[t]);  b1 += w1 * bf2f(r1[t + 256]);
      a2 += w2 * bf2f(r2[t]);  b2 += w2 * bf2f(r2[t + 256]);
      a3 += w3 * bf2f(r3[t]);  b3 += w3 * bf2f(r3[t + 256]);
    }
    for (; j < nchunk; ++j) {
      float w0 = lw_[j];
      const unsigned short* r0 = &xlb[(size_t)ln_[j] * DD];
      a0 += w0 * bf2f(r0[t]);  b0 += w0 * bf2f(r0[t + 256]);
    }
    acc0 += (a0 + a1) + (a2 + a3);
    acc1 += (b0 + b1) + (b2 + b3);
    __syncthreads();
  }
  efb[(size_t)m * DD + t]       = f2bf(acc0);
  efb[(size_t)m * DD + t + 256] = f2bf(acc1);
}

// ---------------- node gather + fused LN1: x1b = LN(x + conv), 4-way unrolled ----------
__global__ __launch_bounds__(256) void gather_node_ln(const int* __restrict__ node_off,
    const int* __restrict__ node_list, const int* __restrict__ edge_idx,
    const float* __restrict__ a_buf, const float* __restrict__ den,
    const unsigned short* __restrict__ efb, const float* __restrict__ bias_h,
    const float* __restrict__ x, const float* __restrict__ g, const float* __restrict__ be,
    unsigned short* __restrict__ x1b) {
  int n = blockIdx.x;
  int t = threadIdx.x;
  int beg = node_off[n], end = node_off[n+1];
  int cnt = end - beg;
  float Dinv = (cnt > 0) ? (1.0f / (float)cnt) : 0.f;
  float wscale = Dinv / (den[n] + 1e-16f);
  __shared__ int   le_[128];
  __shared__ float lw_[128];
  float acc0 = 0.f, acc1 = 0.f;
  for (int c = beg; c < end; c += 128) {
    int nchunk = min(128, end - c);
    if (t < nchunk) {
      int i = node_list[c + t];
      le_[t] = edge_idx[i];
      lw_[t] = a_buf[i] * wscale;
    }
    __syncthreads();
    float a0 = 0.f, a1 = 0.f, a2 = 0.f, a3 = 0.f;
    float b0 = 0.f, b1 = 0.f, b2 = 0.f, b3 = 0.f;
    int j = 0;
    for (; j + 3 < nchunk; j += 4) {
      float w0 = lw_[j], w1 = lw_[j+1], w2 = lw_[j+2], w3 = lw_[j+3];
      const unsigned short* r0 = &efb[(size_t)le_[j]   * DD];
      const unsigned short* r1 = &efb[(size_t)le_[j+1] * DD];
      const unsigned short* r2 = &efb[(size_t)le_[j+2] * DD];
      const unsigned short* r3 = &efb[(size_t)le_[j+3] * DD];
      a0 += w0 * bf2f(r0[t]);  b0 += w0 * bf2f(r0[t + 256]);
      a1 += w1 * bf2f(r1[t]);  b1 += w1 * bf2f(r1[t + 256]);
      a2 += w2 * bf2f(r2[t]);  b2 += w2 * bf2f(r2[t + 256]);
      a3 += w3 * bf2f(r3[t]);  b3 += w3 * bf2f(r3[t + 256]);
    }
    for (; j < nchunk; ++j) {
      float w0 = lw_[j];
      const unsigned short* r0 = &efb[(size_t)le_[j] * DD];
      a0 += w0 * bf2f(r0[t]);  b0 += w0 * bf2f(r0[t + 256]);
    }
    acc0 += (a0 + a1) + (a2 + a3);
    acc1 += (b0 + b1) + (b2 + b3);
    __syncthreads();
  }
  float v0 = x[(size_t)n*DD + t]       + acc0 + bias_h[t];
  float v1 = x[(size_t)n*DD + t + 256] + acc1 + bias_h[t + 256];
  __shared__ float red[4];
  __shared__ float mu_s, rstd_s;
  float s = v0 + v1;
  #pragma unroll
  for (int off = 1; off < 64; off <<= 1) s += __shfl_xor(s, off, 64);
  int wid = t >> 6;
  if ((t & 63) == 0) red[wid] = s;
  __syncthreads();
  if (t == 0) mu_s = (red[0] + red[1] + red[2] + red[3]) / 512.f;
  __syncthreads();
  float mu = mu_s;
  float d0 = v0 - mu, d1 = v1 - mu;
  float vs = d0*d0 + d1*d1;
  #pragma unroll
  for (int off = 1; off < 64; off <<= 1) vs += __shfl_xor(vs, off, 64);
  if ((t & 63) == 0) red[wid] = vs;
  __syncthreads();
  if (t == 0) rstd_s = rsqrtf((red[0] + red[1] + red[2] + red[3]) / 512.f + 1e-5f);
  __syncthreads();
  float rs = rstd_s;
  x1b[(size_t)n*DD + t]       = f2bf(d0 * rs * g[t]       + be[t]);
  x1b[(size_t)n*DD + t + 256] = f2bf(d1 * rs * g[t + 256] + be[t + 256]);
}

// ---------------- LN(a_bf16 + b_bf16) -> bf16 ----------------
__global__ __launch_bounds__(256) void ln_res_bb(const unsigned short* __restrict__ a,
    const unsigned short* __restrict__ b, const float* __restrict__ g,
    const float* __restrict__ be, unsigned short* __restrict__ outb) {
  int r = blockIdx.x;
  int t = threadIdx.x;
  float v0 = bf2f(a[(size_t)r*DD + t])       + bf2f(b[(size_t)r*DD + t]);
  float v1 = bf2f(a[(size_t)r*DD + t + 256]) + bf2f(b[(size_t)r*DD + t + 256]);
  __shared__ float red[4];
  __shared__ float mu_s, rstd_s;
  float s = v0 + v1;
  #pragma unroll
  for (int off = 1; off < 64; off <<= 1) s += __shfl_xor(s, off, 64);
  int wid = t >> 6;
  if ((t & 63) == 0) red[wid] = s;
  __syncthreads();
  if (t == 0) mu_s = (red[0] + red[1] + red[2] + red[3]) / 512.f;
  __syncthreads();
  float mu = mu_s;
  float d0 = v0 - mu, d1 = v1 - mu;
  float vs = d0*d0 + d1*d1;
  #pragma unroll
  for (int off = 1; off < 64; off <<= 1) vs += __shfl_xor(vs, off, 64);
  if ((t & 63) == 0) red[wid] = vs;
  __syncthreads();
  if (t == 0) rstd_s = rsqrtf((red[0] + red[1] + red[2] + red[3]) / 512.f + 1e-5f);
  __syncthreads();
  float rs = rstd_s;
  outb[(size_t)r*DD + t]       = f2bf(d0 * rs * g[t]       + be[t]);
  outb[(size_t)r*DD + t + 256] = f2bf(d1 * rs * g[t + 256] + be[t + 256]);
}

// ---------------- fused final 2 LayerNorms: x3=LN(x2b+ffob); out=LN(x1b+x3) ----------------
__global__ __launch_bounds__(256) void ln_final2(const unsigned short* __restrict__ x2b,
    const unsigned short* __restrict__ ffob, const unsigned short* __restrict__ x1b,
    const float* __restrict__ g1, const float* __restrict__ b1,
    const float* __restrict__ g2, const float* __restrict__ b2,
    float* __restrict__ out) {
  int r = blockIdx.x;
  int t = threadIdx.x;
  __shared__ float red[4];
  __shared__ float sh0, sh1;
  int wid = t >> 6;
  float v0 = bf2f(x2b[(size_t)r*DD + t])       + bf2f(ffob[(size_t)r*DD + t]);
  float v1 = bf2f(x2b[(size_t)r*DD + t + 256]) + bf2f(ffob[(size_t)r*DD + t + 256]);
  float s = v0 + v1;
  #pragma unroll
  for (int off = 1; off < 64; off <<= 1) s += __shfl_xor(s, off, 64);
  if ((t & 63) == 0) red[wid] = s;
  __syncthreads();
  if (t == 0) sh0 = (red[0] + red[1] + red[2] + red[3]) / 512.f;
  __syncthreads();
  float mu = sh0;
  float d0 = v0 - mu, d1 = v1 - mu;
  float vs = d0*d0 + d1*d1;
  #pragma unroll
  for (int off = 1; off < 64; off <<= 1) vs += __shfl_xor(vs, off, 64);
  if ((t & 63) == 0) red[wid] = vs;
  __syncthreads();
  if (t == 0) sh1 = rsqrtf((red[0] + red[1] + red[2] + red[3]) / 512.f + 1e-5f);
  __syncthreads();
  float rs = sh1;
  float x30 = d0 * rs * g1[t]       + b1[t];
  float x31 = d1 * rs * g1[t + 256] + b1[t + 256];
  __syncthreads();
  float u0 = bf2f(x1b[(size_t)r*DD + t])       + x30;
  float u1 = bf2f(x1b[(size_t)r*DD + t + 256]) + x31;
  s = u0 + u1;
  #pragma unroll
  for (int off = 1; off < 64; off <<= 1) s += __shfl_xor(s, off, 64);
  if ((t & 63) == 0) red[wid] = s;
  __syncthreads();
  if (t == 0) sh0 = (red[0] + red[1] + red[2] + red[3]) / 512.f;
  __syncthreads();
  mu = sh0;
  d0 = u0 - mu; d1 = u1 - mu;
  vs = d0*d0 + d1*d1;
  #pragma unroll
  for (int off = 1; off < 64; off <<= 1) vs += __shfl_xor(vs, off, 64);
  if ((t & 63) == 0) red[wid] = vs;
  __syncthreads();
  if (t == 0) sh1 = rsqrtf((red[0] + red[1] + red[2] + red[3]) / 512.f + 1e-5f);
  __syncthreads();
  rs = sh1;
  out[(size_t)r*DD + t]       = d0 * rs * g2[t]       + b2[t];
  out[(size_t)r*DD + t + 256] = d1 * rs * g2[t + 256] + b2[t + 256];
}

// ---------------- MFMA flash attention partial (split-K), KVBLK=64, swapped-QK^T ----
// Round-13 structure exactly (best measured: 82.2 us, single buffer, 2 barriers/tile).
__global__ __launch_bounds__(256) void attn_mfma_part(const unsigned short* __restrict__ qkvbb,
                                                      const unsigned short* __restrict__ Vtb,
                                                      unsigned short* __restrict__ Opartb,
                                                      float* __restrict__ ml) {
  const int head = blockIdx.y;
  const int z = blockIdx.z;
  const int q0 = blockIdx.x * 64;
  const int t = threadIdx.x;
  const int w = t >> 6;
  const int l = t & 63;
  const int lg = l >> 4;
  const int lid = l & 15;
  const float sc = 0.125f * 1.44269504f;    // 1/sqrt(64) * log2(e)
  const float THRraw = 44.36f;              // 8 / sc

  __shared__ __align__(16) unsigned short Kl[64*64];
  __shared__ __align__(16) unsigned short Vl[64*64];

  bf16x8 qa[2];
  {
    const int qrow = q0 + w*16 + lid;
    const unsigned short* qp = &qkvbb[(size_t)qrow*1536 + head*64];
    qa[0] = *(const bf16x8*)&qp[lg*8];
    qa[1] = *(const bf16x8*)&qp[32 + lg*8];
  }

  float m = -1e30f, msc = -1e30f, lsum = 0.f;
  f32x4 o[4];
  #pragma unroll
  for (int dt = 0; dt < 4; ++dt) o[dt] = (f32x4)0.f;

  const unsigned short* Kh = qkvbb + 512 + head*64;          // row stride 1536
  const unsigned short* Vh = Vtb + (size_t)head*64*NN;
  const int kt0 = z * (NN / NSPLIT);
  const int kt1 = kt0 + (NN / NSPLIT);

  const int srow0 = t >> 3,        scc = (t & 7) * 8;
  const int srow1 = 32 + (t >> 3);
  const int sdst0 = (srow0*64 + scc) ^ ((srow0 & 7) << 3);
  const int sdst1 = (srow1*64 + scc) ^ ((srow1 & 7) << 3);
  const int kperm0 = 8*((srow0>>2)&3) + 4*((srow0>>4)&1) + (srow0&3) + 32*(srow0>>5);
  const int kperm1 = 8*((srow1>>2)&3) + 4*((srow1>>4)&1) + (srow1&3) + 32*(srow1>>5);
  ulonglong2 kreg0, kreg1, vreg0, vreg1;

#define LOADKV(ktv) do { \
    kreg0 = *(const ulonglong2*)&Kh[(size_t)((ktv) + kperm0)*1536 + scc]; \
    vreg0 = *(const ulonglong2*)&Vh[(size_t)srow0*NN + (ktv) + scc]; \
    kreg1 = *(const ulonglong2*)&Kh[(size_t)((ktv) + kperm1)*1536 + scc]; \
    vreg1 = *(const ulonglong2*)&Vh[(size_t)srow1*NN + (ktv) + scc]; \
  } while (0)
#define STORKV() do { \
    *(ulonglong2*)&Kl[sdst0] = kreg0; *(ulonglong2*)&Vl[sdst0] = vreg0; \
    *(ulonglong2*)&Kl[sdst1] = kreg1; *(ulonglong2*)&Vl[sdst1] = vreg1; \
  } while (0)

  LOADKV(kt0);
  STORKV();
  __syncthreads();

  for (int kt = kt0; kt < kt1; kt += 64) {
    const bool hn = (kt + 64) < kt1;
    if (hn) LOADKV(kt + 64);   // issue early; lands during compute (T14)

    // ---- S^T = K Q^T (swapped operands) ----
    f32x4 s[4];
    #pragma unroll
    for (int n = 0; n < 4; ++n) s[n] = (f32x4)0.f;
    __builtin_amdgcn_s_setprio(1);
    #pragma unroll
    for (int n = 0; n < 4; ++n) {
      int tok = n*16 + lid;
      #pragma unroll
      for (int hf = 0; hf < 2; ++hf) {
        int didx = (tok*64 + hf*32 + lg*8) ^ ((tok & 7) << 3);
        bf16x8 kb = *(const bf16x8*)&Kl[didx];
        s[n] = __builtin_amdgcn_mfma_f32_16x16x32_bf16(kb, qa[hf], s[n], 0, 0, 0);
      }
    }
    __builtin_amdgcn_s_setprio(0);

    // ---- in-register online softmax, raw units (q = lid per lane) ----
    float a0 = fmaxf(fmaxf(s[0][0], s[0][1]), s[0][2]);
    float a1 = fmaxf(fmaxf(s[0][3], s[1][0]), s[1][1]);
    float a2 = fmaxf(fmaxf(s[1][2], s[1][3]), s[2][0]);
    float a3 = fmaxf(fmaxf(s[2][1], s[2][2]), s[2][3]);
    float a4 = fmaxf(fmaxf(s[3][0], s[3][1]), s[3][2]);
    float mx = fmaxf(fmaxf(fmaxf(a0, a1), a2), fmaxf(fmaxf(a3, a4), s[3][3]));
    mx = fmaxf(mx, __shfl_xor(mx, 16, 64));
    mx = fmaxf(mx, __shfl_xor(mx, 32, 64));
    if (!__all(mx <= m + THRraw)) {
      float mn = fmaxf(m, mx);
      float c = exp2f((m - mn) * sc);
      m = mn;
      msc = m * sc;
      lsum *= c;
      #pragma unroll
      for (int r = 0; r < 4; ++r) {
        float cr = __shfl(c, lg*4 + r, 64);
        #pragma unroll
        for (int dt = 0; dt < 4; ++dt) o[dt][r] *= cr;
      }
    }
    float ps = 0.f;
    #pragma unroll
    for (int n = 0; n < 4; ++n)
      #pragma unroll
      for (int r = 0; r < 4; ++r) {
        float p = exp2f(fmaf(s[n][r], sc, -msc));
        s[n][r] = p;
        ps += p;
      }
    ps += __shfl_xor(ps, 16, 64);
    ps += __shfl_xor(ps, 32, 64);
    lsum += ps;

    // ---- P repack: fully in-lane (thanks to K row permutation) ----
    union { bf16x8 v; unsigned int u[4]; } pa[2];
    #pragma unroll
    for (int hf = 0; hf < 2; ++hf) {
      asm("v_cvt_pk_bf16_f32 %0, %1, %2" : "=v"(pa[hf].u[0]) : "v"(s[2*hf][0]),   "v"(s[2*hf][1]));
      asm("v_cvt_pk_bf16_f32 %0, %1, %2" : "=v"(pa[hf].u[1]) : "v"(s[2*hf][2]),   "v"(s[2*hf][3]));
      asm("v_cvt_pk_bf16_f32 %0, %1, %2" : "=v"(pa[hf].u[2]) : "v"(s[2*hf+1][0]), "v"(s[2*hf+1][1]));
      asm("v_cvt_pk_bf16_f32 %0, %1, %2" : "=v"(pa[hf].u[3]) : "v"(s[2*hf+1][2]), "v"(s[2*hf+1][3]));
    }

    // ---- O += P V ----
    __builtin_amdgcn_s_setprio(1);
    #pragma unroll
    for (int dt = 0; dt < 4; ++dt) {
      int drow = dt*16 + lid;
      #pragma unroll
      for (int hf = 0; hf < 2; ++hf) {
        int didx = (drow*64 + hf*32 + lg*8) ^ ((drow & 7) << 3);
        bf16x8 vb = *(const bf16x8*)&Vl[didx];
        o[dt] = __builtin_amdgcn_mfma_f32_16x16x32_bf16(pa[hf].v, vb, o[dt], 0, 0, 0);
      }
    }
    __builtin_amdgcn_s_setprio(0);

    __syncthreads();           // all waves done reading Kl/Vl
    if (hn) {
      STORKV();                // write prefetched tile
      __syncthreads();
    }
  }
#undef LOADKV
#undef STORKV

  // ---- epilogue: bf16 partial O (rows q=lg*4+r) + per-lane (msc, l) for q=lid ----
  #pragma unroll
  for (int r = 0; r < 4; ++r) {
    int q = q0 + w*16 + lg*4 + r;
    size_t base = ((size_t)(z*HH + head)*NN + q)*64;
    #pragma unroll
    for (int dt = 0; dt < 4; ++dt)
      Opartb[base + dt*16 + lid] = f2bf(o[dt][r]);
  }
  if (l < 16) {
    int q = q0 + w*16 + l;
    size_t mb = ((size_t)(z*HH + head)*NN + q)*2;
    ml[mb]     = msc;
    ml[mb + 1] = lsum;
  }
}

// ---------------- combine split-K partials -> ctx bf16 ----------------
__global__ __launch_bounds__(256) void attn_combine(const unsigned short* __restrict__ Opartb,
                                                    const float* __restrict__ ml,
                                                    unsigned short* __restrict__ ctxb) {
  const int w = threadIdx.x >> 6, lane = threadIdx.x & 63;
  const int row = blockIdx.x * 4 + w;     // 0 .. NN*HH-1
  const int q = row >> 3, head = row & 7;
  float ms[NSPLIT], ls[NSPLIT];
  float mglob = -1e30f;
  #pragma unroll
  for (int s = 0; s < NSPLIT; ++s) {
    size_t mb = ((size_t)(s*HH + head)*NN + q)*2;
    ms[s] = ml[mb]; ls[s] = ml[mb + 1];
    mglob = fmaxf(mglob, ms[s]);
  }
  float lt = 0.f, ov = 0.f;
  #pragma unroll
  for (int s = 0; s < NSPLIT; ++s) {
    float wgt = exp2f(ms[s] - mglob);
    lt += ls[s] * wgt;
    ov += bf2f(Opartb[((size_t)(s*HH + head)*NN + q)*64 + lane]) * wgt;
  }
  ctxb[(size_t)q*DD + head*64 + lane] = f2bf(ov / lt);
}

// ---------------- host ----------------
extern "C" void kernel_launch(void* const* d_in, const int* in_sizes, int n_in,
                              void* d_out, int out_size, void* d_ws, size_t ws_size,
                              hipStream_t stream) {
  const float* x       = (const float*)d_in[0];
  const int*   hidx    = (const int*)d_in[1];
  const float* hattr   = (const float*)d_in[2];
  const float* Wh      = (const float*)d_in[3];
  const float* att     = (const float*)d_in[4];
  const float* bias_h  = (const float*)d_in[5];
  const float* ln1_g   = (const float*)d_in[6];
  const float* ln1_b   = (const float*)d_in[7];
  const float* ln2_g   = (const float*)d_in[8];
  const float* ln2_b   = (const float*)d_in[9];
  const float* in_proj_w  = (const float*)d_in[10];
  const float* in_proj_b  = (const float*)d_in[11];
  const float* out_proj_w = (const float*)d_in[12];
  const float* out_proj_b = (const float*)d_in[13];
  const float* ff1_w   = (const float*)d_in[14];
  const float* ff1_b   = (const float*)d_in[15];
  const float* ff2_w   = (const float*)d_in[16];
  const float* ff2_b   = (const float*)d_in[17];
  const float* tln1_g  = (const float*)d_in[18];
  const float* tln1_b  = (const float*)d_in[19];
  const float* tln2_g  = (const float*)d_in[20];
  const float* tln2_b  = (const float*)d_in[21];
  const int* node_idx = hidx;
  const int* edge_idx = hidx + NNZC;

  char* ws = (char*)d_ws;
  size_t off = 0;
  auto alloc = [&](size_t bytes) -> void* {
    void* p = ws + off;
    off = (off + bytes + 63) & ~(size_t)63;
    return p;
  };
  float* s_node   = (float*)alloc(sizeof(float)*NN);
  float* s_edge   = (float*)alloc(sizeof(float)*MM);
  float* a_buf    = (float*)alloc(sizeof(float)*NNZC);
  float* amax     = (float*)alloc(sizeof(float)*NN);
  float* den      = (float*)alloc(sizeof(float)*NN);
  int*   DnCnt    = (int*)alloc(sizeof(int)*NN);
  int*   BnCnt    = (int*)alloc(sizeof(int)*MM);
  int*   node_off = (int*)alloc(sizeof(int)*(NN+1));
  int*   edge_off = (int*)alloc(sizeof(int)*(MM+1));
  int*   node_cur = (int*)alloc(sizeof(int)*NN);
  int*   edge_cur = (int*)alloc(sizeof(int)*MM);
  int*   node_list= (int*)alloc(sizeof(int)*NNZC);
  int*   edge_list= (int*)alloc(sizeof(int)*NNZC);
  unsigned short* xhb   = (unsigned short*)alloc(sizeof(unsigned short)*(NN+MM)*DD);  // [x; hattr]
  unsigned short* xelb  = (unsigned short*)alloc(sizeof(unsigned short)*(NN+MM)*DD);  // [xl; el]
  unsigned short* efb   = (unsigned short*)alloc(sizeof(unsigned short)*MM*DD);
  unsigned short* qkvbb = (unsigned short*)alloc(sizeof(unsigned short)*NN*3*DD);
  unsigned short* Vtb   = (unsigned short*)alloc(sizeof(unsigned short)*NN*DD);
  unsigned short* Whb   = (unsigned short*)alloc(sizeof(unsigned short)*DD*DD);
  unsigned short* ipwb  = (unsigned short*)alloc(sizeof(unsigned short)*3*DD*DD);
  unsigned short* opwb  = (unsigned short*)alloc(sizeof(unsigned short)*DD*DD);
  unsigned short* ff1wb = (unsigned short*)alloc(sizeof(unsigned short)*DFFC*DD);
  unsigned short* ff2wb = (unsigned short*)alloc(sizeof(unsigned short)*DD*DFFC);
  unsigned short* x1b   = (unsigned short*)alloc(sizeof(unsigned short)*NN*DD);
  unsigned short* x2b   = (unsigned short*)alloc(sizeof(unsigned short)*NN*DD);
  unsigned short* ctxb  = (unsigned short*)alloc(sizeof(unsigned short)*NN*DD);
  unsigned short* attn_outb = (unsigned short*)alloc(sizeof(unsigned short)*NN*DD);
  // "late" region: attention partials alias FFN-phase buffers (dead before ff1).
  char* late = (char*)alloc(20u*1024*1024);
  unsigned short* Opartb = (unsigned short*)late;                        // 16 MB (attn phase)
  float*          mlb    = (float*)(late + 16u*1024*1024);               // 1 MB (attn phase)
  unsigned short* ffhb   = (unsigned short*)late;                        // 16 MB (FFN phase)
  unsigned short* ffob   = (unsigned short*)(late + 16u*1024*1024);      // 4 MB (FFN phase)
  unsigned short* xlb = xelb;
  unsigned short* elb = xelb + (size_t)NN*DD;
  (void)ws_size; (void)in_sizes; (void)n_in; (void)out_size;

  dim3 b256(256);
  // one-time bf16 conversions (single batched launch); x and hattr land adjacent in xhb
  f2b_multi<<<dim3(256, 7), b256, 0, stream>>>(
      x, xhb, NN*DD/8,  hattr, xhb + (size_t)NN*DD, MM*DD/8,  Wh, Whb, DD*DD/8,
      in_proj_w, ipwb, 3*DD*DD/8,  out_proj_w, opwb, DD*DD/8,
      ff1_w, ff1wb, DFFC*DD/8,  ff2_w, ff2wb, DD*DFFC/8);

  // [xl; el] = [x; hattr] @ Wh^T  (merged, BN=64)
  gemm_bt_bf16_n64<<<dim3((NN+MM)/128, DD/64), b256, 0, stream>>>(xhb, Whb, nullptr, xelb, DD, DD, nullptr);
  // sparse hypergraph conv
  rowdot_both<<<(NN+MM)/4, b256, 0, stream>>>(xlb, elb, att, s_node, s_edge);
  init_kernel<<<NN/256, b256, 0, stream>>>(amax, den, DnCnt, BnCnt, node_cur, edge_cur);
  incidence_pass1<<<NNZC/256, b256, 0, stream>>>(node_idx, edge_idx, s_node, s_edge,
                                                 a_buf, amax, DnCnt, BnCnt);
  exscan2_kernel<<<2, 1024, 0, stream>>>(DnCnt, node_off, NN, BnCnt, edge_off, MM);
  incidence_pass2<<<NNZC/256, b256, 0, stream>>>(node_idx, edge_idx, a_buf, amax, den,
                                                 node_off, edge_off, node_cur, edge_cur,
                                                 node_list, edge_list);
  gather_edge<<<MM, b256, 0, stream>>>(edge_off, edge_list, node_idx, a_buf, den, xlb, efb);
  // gather_node + fused LN1 -> x1b (bf16 residual stream)
  gather_node_ln<<<NN, b256, 0, stream>>>(node_off, node_list, edge_idx, a_buf, den, efb,
                                          bias_h, x, ln1_g, ln1_b, x1b);
  // qkv (BN=64; V-plane blocks write transposed Vtb directly)
  gemm_bt_bf16_n64<<<dim3(NN/128, (3*DD)/64), b256, 0, stream>>>(x1b, ipwb, in_proj_b, qkvbb, 3*DD, DD, Vtb);
  // attention (bf16 MFMA, split-K x4, KVBLK=64 + combine)
  attn_mfma_part<<<dim3(NN/64, HH, NSPLIT), b256, 0, stream>>>(qkvbb, Vtb, Opartb, mlb);
  attn_combine<<<NN*HH/4, b256, 0, stream>>>(Opartb, mlb, ctxb);
  // out_proj (BN=64)
  gemm_bt_bf16_n64<<<dim3(NN/128, DD/64), b256, 0, stream>>>(ctxb, opwb, out_proj_b, attn_outb, DD, DD, nullptr);
  // x2b = LN(x1b + attn_outb)
  ln_res_bb<<<NN, b256, 0, stream>>>(x1b, attn_outb, tln1_g, tln1_b, x2b);
  // ffn: ff1 (128x128 tile; relu, bf16 out), ff2 (BN=64, K=2048)
  gemm_bt_bf16<<<dim3(NN/128, DFFC/128), b256, 0, stream>>>(x2b, ff1wb, ff1_b, nullptr, ffhb, DFFC, DD, 1);
  gemm_bt_bf16_n64<<<dim3(NN/128, DD/64), b256, 0, stream>>>(ffhb, ff2wb, ff2_b, ffob, DD, DFFC, nullptr);
  // x3 = LN(x2b + ffob); out = LN(x1b + x3)  (fused)
  ln_final2<<<NN, b256, 0, stream>>>(x2b, ffob, x1b, tln2_g, tln2_b, ln2_g, ln2_b, (float*)d_out);
}